// Round 7
// baseline (539.037 us; speedup 1.0000x reference)
//
#include <hip/hip_runtime.h>
#include <hip/hip_bf16.h>
#include <hip/hip_fp16.h>

// ---------------------------------------------------------------------------
// 3-layer GAT encoder. N=50000, E=1600000 (+N self loops), H=2 (layers 1-2),
// F=64 per head, F_IN=128.
// R13: deterministic counting-sort CSR + fused gather/GEMM: 337us.
// R16: h fp8 e4m3 -> gg FETCH 61.5MB, 52.5us, total 294us. BEST.
// R17/R18 NEG: gather at latency-concurrency equilibrium; VALU/VMEM count
//      non-binding. R19 FAILED: atomic scatter -> 107MB write-allocate.
// R20: gg FETCH decomposition: 51MB of 61.5MB is the 6.4MB h table
//      re-fetched by all 8 XCD L2s. Fix: planar h (8 col-planes x 16B/row,
//      800KB/plane) + 8 column-group gather slices pinned to XCDs via
//      blockIdx%8 -> h reads become L2 hits. csr -> ushort (src<65536) to
//      cheapen the x8 csr re-read. Gather and GEMM split: gslice writes
//      planar fp16 act; gemm_l (streaming, MFMA, identical epilogue)
//      produces next planar h + alS/alD. gather_out sliced into 4 planes.
//      CSR build chain reverted to the proven deterministic counting sort.
// ---------------------------------------------------------------------------

#define ELU(x) ((x) > 0.f ? (x) : (__expf(x) - 1.f))
#define BSH 8                       // 256 nodes per bucket
#define CHK 8192                    // edges per histogram/partition block

typedef _Float16 f16x8 __attribute__((ext_vector_type(8)));
typedef float    f32x4 __attribute__((ext_vector_type(4)));
typedef float    f32x2 __attribute__((ext_vector_type(2)));

// pack 4 f16 (as 2 half2) -> 4 fp8 e4m3 in one dword (RNE in HW)
__device__ inline unsigned int f16x4_to_fp8(__half2 h0, __half2 h1) {
    float2 a = __half22float2(h0), b = __half22float2(h1);
    unsigned int r = __builtin_amdgcn_cvt_pk_fp8_f32(a.x, a.y, 0, false);
    r = __builtin_amdgcn_cvt_pk_fp8_f32(b.x, b.y, r, true);
    return r;
}

// ---------------- phase0: Wt builds + per-block dst histogram rows ---------
__global__ __launch_bounds__(256) void phase0(
    const float* __restrict__ W1, __half* __restrict__ Wt1,
    const float* __restrict__ W2, __half* __restrict__ Wt2,
    const float* __restrict__ W3, __half* __restrict__ Wt3,
    const int* __restrict__ ei, int* __restrict__ bhist_rows, int E_)
{
    const int t = threadIdx.x;
    const int b = blockIdx.x;
    if (b < 160) {                                   // Wt[n][k] = (h) W[k][n]
        const float* W; __half* Wt; int N, base;
        if (b < 64)       { W = W1; Wt = Wt1; N = 128; base = b; }
        else if (b < 128) { W = W2; Wt = Wt2; N = 128; base = b - 64; }
        else              { W = W3; Wt = Wt3; N = 64;  base = b - 128; }
        int idx = base * 256 + t;
        if (idx < N * 128) {
            int nn = idx >> 7, k = idx & 127;
            Wt[idx] = __float2half(W[k * N + nn]);
        }
    } else {                                         // dst histogram row
        __shared__ int cnt[256];
        int hb = b - 160;
        cnt[t] = 0;
        __syncthreads();
        const int e0 = hb * CHK;
        for (int i = t; i < CHK; i += 256) {
            int e = e0 + i;
            if (e >= E_) break;
            atomicAdd(&cnt[ei[E_ + e] >> BSH], 1);
        }
        __syncthreads();
        bhist_rows[hb * 256 + t] = cnt[t];
    }
}

// one block per bucket: (a) bucket totals + scan (block 0 writes boff),
// (b) column scan of this bucket -> per-partition-block bases,
// (c) self-loop part entries at bucket tail. HB <= 256.
__global__ __launch_bounds__(256) void scan_bases(
    const int* __restrict__ bhist_rows, int* __restrict__ boff,
    int* __restrict__ bases, int* __restrict__ part, int HB, int n, int NB)
{
    __shared__ int tot[256];
    __shared__ int col[256];
    const int t = threadIdx.x;
    const int b = blockIdx.x;                        // bucket

    // bucket totals (+ self loops), inclusive scan
    int v = 0;
    for (int r = 0; r < HB; r++) v += bhist_rows[r * 256 + t];
    int nodes_t = n - (t << BSH);
    nodes_t = nodes_t < 0 ? 0 : (nodes_t > 256 ? 256 : nodes_t);
    v = (t < NB) ? (v + nodes_t) : 0;
    tot[t] = v;
    __syncthreads();
    for (int d = 1; d < 256; d <<= 1) {
        int x = (t >= d) ? tot[t - d] : 0;
        __syncthreads();
        tot[t] += x;
        __syncthreads();
    }
    if (b == 0) {
        if (t < NB) boff[t + 1] = tot[t];
        if (t == 0) boff[0] = 0;
    }
    const int base0 = (b > 0) ? tot[b - 1] : 0;      // boff[b]
    const int bend  = tot[b];                        // boff[b+1]

    // column scan for this bucket -> bases
    int c = (t < HB) ? bhist_rows[t * 256 + b] : 0;
    col[t] = c;
    __syncthreads();
    for (int d = 1; d < 256; d <<= 1) {
        int x = (t >= d) ? col[t - d] : 0;
        __syncthreads();
        col[t] += x;
        __syncthreads();
    }
    if (t < HB) bases[b * HB + t] = base0 + col[t] - c;   // exclusive

    // self loops at bucket tail (coalesced); src < 65536 fits low 16 bits
    const int n0 = b << BSH;
    const int nodes = min(256, n - n0);
    const int sl0 = bend - nodes;
    if (t < nodes) part[sl0 + t] = (n0 + t) | (t << 16);
}

// single-pass partition: deterministic bases, LDS-local cursors only.
// packed entry: src (bits 0..15) | dst_local (bits 16..23)
__global__ __launch_bounds__(256) void edge_partition(
    const int* __restrict__ ei, const int* __restrict__ bases,
    int* __restrict__ part, int E_, int HB, int NB)
{
    __shared__ int cnt[256];
    __shared__ int sbase[256];
    const int t = threadIdx.x;
    const int hb = blockIdx.x;
    cnt[t] = 0;
    sbase[t] = (t < NB) ? bases[t * HB + hb] : 0;
    __syncthreads();
    const int e0 = hb * CHK;
    for (int i = t; i < CHK; i += 256) {
        int e = e0 + i;
        if (e >= E_) break;
        int src = ei[e], dst = ei[E_ + e];
        int b = dst >> BSH;
        int pos = sbase[b] + atomicAdd(&cnt[b], 1);
        part[pos] = src | ((dst & 255) << 16);
    }
}

// one block per bucket: per-node degree count, LDS scan -> off[], place, flush
// csr output is ushort (src < 65536).
__global__ __launch_bounds__(256) void bucket_fill(
    const int* __restrict__ boff, const int* __restrict__ part,
    unsigned short* __restrict__ csr, int* __restrict__ off, int n)
{
    __shared__ int sm[256];
    __shared__ int cur[256];
    __shared__ int slice[12544];
    const int t = threadIdx.x;
    const int b = blockIdx.x;
    const int n0 = b << BSH;
    const int nodes = min(256, n - n0);
    const int off0 = boff[b];
    const int sz = boff[b + 1] - off0;

    cur[t] = 0;
    __syncthreads();
    for (int i = t; i < sz; i += 256)
        atomicAdd(&cur[(part[off0 + i] >> 16) & 255], 1);
    __syncthreads();
    int v = cur[t];
    sm[t] = v;
    __syncthreads();
    for (int d = 1; d < 256; d <<= 1) {
        int x = (t >= d) ? sm[t - d] : 0;
        __syncthreads();
        sm[t] += x;
        __syncthreads();
    }
    const int excl = sm[t] - v;
    if (t < nodes) off[n0 + t] = off0 + excl;
    if (t == nodes - 1) off[n0 + nodes] = off0 + sz;
    cur[t] = excl;
    __syncthreads();

    if (sz <= 12544) {
        for (int i = t; i < sz; i += 256) {
            int p  = part[off0 + i];
            int dl = (p >> 16) & 255;
            int pos = atomicAdd(&cur[dl], 1);
            slice[pos] = p & 0xFFFF;
        }
        __syncthreads();
        for (int i = t; i < sz; i += 256)
            csr[off0 + i] = (unsigned short)slice[i];
    } else {                                     // fallback (shouldn't trigger)
        for (int i = t; i < sz; i += 256) {
            int p  = part[off0 + i];
            int dl = (p >> 16) & 255;
            int pos = atomicAdd(&cur[dl], 1);
            csr[off0 + pos] = (unsigned short)(p & 0xFFFF);
        }
    }
}

// ---------------- layer-1 MFMA GEMM (fp32 A, LDS W) -> planar fp8 h1 -------
__global__ __launch_bounds__(256) void gemm1_mfma(
    const float* __restrict__ A, const __half* __restrict__ Wt, // [128][128]
    unsigned char* __restrict__ Hout, int psz,
    const float* __restrict__ a_s, const float* __restrict__ a_d,
    float* __restrict__ alS, float* __restrict__ alD, int nrows)
{
    constexpr int N = 128, NT = 8, WR = 136;
    __shared__ _Float16 wt[N * WR];
    __shared__ _Float16 hst[4][16 * WR];

    const int t = threadIdx.x, w = t >> 6, l = t & 63;
    const int q = l >> 4, n = l & 15;
    const int node0 = blockIdx.x * 64;
    const int row_base = node0 + w * 16;

    for (int i = t; i < N * 16; i += 256) {
        int r = i >> 4, c = i & 15;
        float4 v = *(const float4*)&Wt[r * 128 + c * 8];
        *(float4*)&wt[r * WR + c * 8] = v;
    }
    __syncthreads();

    f32x4 acc[NT];
#pragma unroll
    for (int ct = 0; ct < NT; ct++) acc[ct] = (f32x4){0.f, 0.f, 0.f, 0.f};

    int arow = row_base + n; if (arow >= nrows) arow = nrows - 1;
    const float* Ap = A + (size_t)arow * 128 + q * 8;
#pragma unroll
    for (int ks = 0; ks < 4; ks++) {
        float4 va = *(const float4*)(Ap + ks * 32);
        float4 vb = *(const float4*)(Ap + ks * 32 + 4);
        f16x8 a = { (_Float16)va.x, (_Float16)va.y, (_Float16)va.z, (_Float16)va.w,
                    (_Float16)vb.x, (_Float16)vb.y, (_Float16)vb.z, (_Float16)vb.w };
#pragma unroll
        for (int ct = 0; ct < NT; ct++) {
            f16x8 bb = *(const f16x8*)&wt[(ct * 16 + n) * WR + ks * 32 + q * 8];
            acc[ct] = __builtin_amdgcn_mfma_f32_16x16x32_f16(a, bb, acc[ct], 0, 0, 0);
        }
    }

    float asv[NT], adv[NT];
#pragma unroll
    for (int ct = 0; ct < NT; ct++) {
        asv[ct] = a_s[ct * 16 + n];
        adv[ct] = a_d[ct * 16 + n];
    }
#pragma unroll
    for (int r = 0; r < 4; r++) {
        int grow = row_base + q * 4 + r;
        float s0 = 0.f, d0 = 0.f, s1 = 0.f, d1 = 0.f;
#pragma unroll
        for (int ct = 0; ct < NT; ct++) {
            float v = acc[ct][r];
            float ps = v * asv[ct], pd = v * adv[ct];
            if (ct >= 4) { s1 += ps; d1 += pd; }
            else         { s0 += ps; d0 += pd; }
        }
#pragma unroll
        for (int m = 1; m < 16; m <<= 1) {
            s0 += __shfl_xor(s0, m); d0 += __shfl_xor(d0, m);
            s1 += __shfl_xor(s1, m); d1 += __shfl_xor(d1, m);
        }
        if (n == 0 && grow < nrows) {
            alS[grow * 2] = s0;     alD[grow * 2] = d0;
            alS[grow * 2 + 1] = s1; alD[grow * 2 + 1] = d1;
        }
    }

#pragma unroll
    for (int ct = 0; ct < NT; ct++)
#pragma unroll
        for (int r = 0; r < 4; r++)
            hst[w][(q * 4 + r) * WR + ct * 16 + n] = (_Float16)acc[ct][r];
    __syncthreads();
    {
        int row = l >> 2, c = l & 3;            // 4 lanes x 32 cols
        int grow = row_base + row;
        if (grow < nrows) {
#pragma unroll
            for (int i = 0; i < 4; i++) {
                float4 v = *(float4*)&hst[w][row * WR + c * 32 + i * 8];
                const __half2* hp = (const __half2*)&v;
                uint2 o;
                o.x = f16x4_to_fp8(hp[0], hp[1]);
                o.y = f16x4_to_fp8(hp[2], hp[3]);
                int cb = c * 32 + i * 8;        // byte col
                *(uint2*)&Hout[(size_t)(cb >> 4) * psz + (size_t)grow * 16 + (cb & 15)] = o;
            }
        }
    }
}

// ---------------- gslice: XCD-pinned column-slice gather -------------------
// 8 column groups (16 fp8 cols each); g = blockIdx%8 -> XCD g round-robin,
// so each XCD's L2 holds only plane g (800KB) -> h reads are L2 hits.
// 1 lane per node, uint4 per edge, depth-2 pair prefetch. Writes planar
// fp16 act (16 cols = 32B) after inv+bias+ELU.
__global__ __launch_bounds__(256) void gslice(
    const int* __restrict__ off, const unsigned short* __restrict__ csr,
    const unsigned char* __restrict__ hpl, int psz,
    const float* __restrict__ alS, const float* __restrict__ alD,
    const float* __restrict__ bias, unsigned char* __restrict__ ap,
    int apsz, int n)
{
    const int g = blockIdx.x & 7;
    const int node = (blockIdx.x >> 3) * 256 + threadIdx.x;
    if (node >= n) return;
    const int head = g >> 2;
    const float ad = alD[node * 2 + head];
    const int s0 = off[node], s1 = off[node + 1];
    const int last = s1 - 1;
    const unsigned char* hp = hpl + (size_t)g * psz;

    float a[16];
#pragma unroll
    for (int i = 0; i < 16; i++) a[i] = 0.f;
    float wsum = 0.f;

    auto accum = [&](const uint4& vv, float w) {
        unsigned int dw[4] = { vv.x, vv.y, vv.z, vv.w };
#pragma unroll
        for (int d = 0; d < 4; d++) {
            f32x2 lo = __builtin_amdgcn_cvt_pk_f32_fp8(dw[d], false);
            f32x2 hi = __builtin_amdgcn_cvt_pk_f32_fp8(dw[d], true);
            a[d * 4 + 0] = fmaf(w, lo.x, a[d * 4 + 0]);
            a[d * 4 + 1] = fmaf(w, lo.y, a[d * 4 + 1]);
            a[d * 4 + 2] = fmaf(w, hi.x, a[d * 4 + 2]);
            a[d * 4 + 3] = fmaf(w, hi.y, a[d * 4 + 3]);
        }
        wsum += w;
    };

    int sA0 = csr[s0];
    int sA1 = csr[s0 + 1 <= last ? s0 + 1 : last];
    uint4 vA0 = *(const uint4*)(hp + sA0 * 16);
    uint4 vA1 = *(const uint4*)(hp + sA1 * 16);
    float aA0 = alS[sA0 * 2 + head];
    float aA1 = alS[sA1 * 2 + head];

    for (int j = s0; j < s1; j += 2) {
        int jn0 = j + 2 <= last ? j + 2 : last;
        int jn1 = j + 3 <= last ? j + 3 : last;
        int sB0 = csr[jn0], sB1 = csr[jn1];
        uint4 vB0 = *(const uint4*)(hp + sB0 * 16);
        uint4 vB1 = *(const uint4*)(hp + sB1 * 16);
        float aB0 = alS[sB0 * 2 + head];
        float aB1 = alS[sB1 * 2 + head];

        {   // edge j (always valid)
            float e = aA0 + ad; e = e > 0.f ? e : 0.2f * e;
            accum(vA0, __expf(e));
        }
        {   // edge j+1
            float e = aA1 + ad; e = e > 0.f ? e : 0.2f * e;
            float w = (j + 1 <= last) ? __expf(e) : 0.f;
            accum(vA1, w);
        }
        sA0 = sB0; sA1 = sB1; vA0 = vB0; vA1 = vB1; aA0 = aB0; aA1 = aB1;
    }

    const float inv = 1.f / (wsum + 1e-16f);
    const int c0f = g * 16;
    float bb[16];
    *(float4*)&bb[0]  = *(const float4*)&bias[c0f];
    *(float4*)&bb[4]  = *(const float4*)&bias[c0f + 4];
    *(float4*)&bb[8]  = *(const float4*)&bias[c0f + 8];
    *(float4*)&bb[12] = *(const float4*)&bias[c0f + 12];
    __half2 p[8];
#pragma unroll
    for (int i = 0; i < 8; i++) {
        float o0 = ELU(fmaf(a[2 * i],     inv, bb[2 * i]));
        float o1 = ELU(fmaf(a[2 * i + 1], inv, bb[2 * i + 1]));
        p[i] = __floats2half2_rn(o0, o1);
    }
    unsigned char* apg = ap + (size_t)g * apsz + (size_t)node * 32;
    *(float4*)apg        = *(float4*)&p[0];
    *(float4*)(apg + 16) = *(float4*)&p[4];
}

// ---------------- gemm_l: planar fp16 act -> MFMA -> planar fp8 h + alS ----
template<int OUTN>
__global__ __launch_bounds__(256) void gemm_l(
    const unsigned char* __restrict__ ap, int apsz,
    const __half* __restrict__ Wt, const float* __restrict__ a_s,
    const float* __restrict__ a_d, unsigned char* __restrict__ Hout,
    int psz, float* __restrict__ alSo, float* __restrict__ alDo, int n)
{
    constexpr int WR = 136;
    constexpr int CTW = OUTN / 64;        // col-tiles per wave
    constexpr int CPW = OUTN / 4;         // cols per wave
    __shared__ _Float16 actT[16 * WR];
    __shared__ float red_s[4][16], red_d[4][16];

    const int t = threadIdx.x;
    const int node0 = blockIdx.x * 16;

    {   // stage 16 act rows (8 planes x 32B) -> LDS
        int p = t >> 5, r = (t >> 1) & 15, half = t & 1;
        int grow = node0 + r; if (grow >= n) grow = n - 1;
        float4 v = *(const float4*)(ap + (size_t)p * apsz + (size_t)grow * 32 + half * 16);
        *(float4*)&actT[r * WR + p * 16 + half * 8] = v;
    }
    __syncthreads();

    const int w = t >> 6, l64 = t & 63, q = l64 >> 4, nn = l64 & 15;
    const __half* Wp = Wt + (size_t)(w * CPW + nn) * 128 + q * 8;
    f32x4 acc[CTW];
#pragma unroll
    for (int ct = 0; ct < CTW; ct++) acc[ct] = (f32x4){0.f, 0.f, 0.f, 0.f};
#pragma unroll
    for (int ks = 0; ks < 4; ks++) {
        f16x8 a = *(const f16x8*)&actT[nn * WR + ks * 32 + q * 8];
#pragma unroll
        for (int ct = 0; ct < CTW; ct++) {
            f16x8 bb = *(const f16x8*)(Wp + ct * 16 * 128 + ks * 32);
            acc[ct] = __builtin_amdgcn_mfma_f32_16x16x32_f16(a, bb, acc[ct], 0, 0, 0);
        }
    }

    float asv[CTW], adv2[CTW];
#pragma unroll
    for (int ct = 0; ct < CTW; ct++) {
        asv[ct]  = a_s[w * CPW + ct * 16 + nn];
        adv2[ct] = a_d[w * CPW + ct * 16 + nn];
    }
#pragma unroll
    for (int r = 0; r < 4; r++) {
        float s = 0.f, d = 0.f;
#pragma unroll
        for (int ct = 0; ct < CTW; ct++) {
            float vv = acc[ct][r];
            s = fmaf(vv, asv[ct], s);
            d = fmaf(vv, adv2[ct], d);
        }
#pragma unroll
        for (int m = 1; m < 16; m <<= 1) {
            s += __shfl_xor(s, m);
            d += __shfl_xor(d, m);
        }
        if (nn == 0) { red_s[w][q * 4 + r] = s; red_d[w][q * 4 + r] = d; }
    }
    __syncthreads();

    // stage output into actT (reuse)
#pragma unroll
    for (int ct = 0; ct < CTW; ct++)
#pragma unroll
        for (int r = 0; r < 4; r++)
            actT[(q * 4 + r) * WR + w * CPW + ct * 16 + nn] = (_Float16)acc[ct][r];
    if (OUTN == 128) {
        if (t < 32) {
            int m = t & 15, hh = t >> 4;
            int grow = node0 + m;
            if (grow < n) {
                alSo[grow * 2 + hh] = red_s[2 * hh][m] + red_s[2 * hh + 1][m];
                alDo[grow * 2 + hh] = red_d[2 * hh][m] + red_d[2 * hh + 1][m];
            }
        }
    } else {
        if (t < 16) {
            int grow = node0 + t;
            if (grow < n) {
                alSo[grow] = red_s[0][t] + red_s[1][t] + red_s[2][t] + red_s[3][t];
                alDo[grow] = red_d[0][t] + red_d[1][t] + red_d[2][t] + red_d[3][t];
            }
        }
    }
    __syncthreads();

    // planar fp8 Hout store
    if (OUTN == 128) {
        int row = t >> 4, c = t & 15;          // byte col cb = c*8
        int grow = node0 + row;
        if (grow < n) {
            float4 v8 = *(float4*)&actT[row * WR + c * 8];
            const __half2* hp = (const __half2*)&v8;
            uint2 o;
            o.x = f16x4_to_fp8(hp[0], hp[1]);
            o.y = f16x4_to_fp8(hp[2], hp[3]);
            *(uint2*)&Hout[(size_t)(c >> 1) * psz + (size_t)grow * 16 + (c & 1) * 8] = o;
        }
    } else {
        if (t < 128) {
            int row = t >> 3, c = t & 7;       // byte col cb = c*8
            int grow = node0 + row;
            if (grow < n) {
                float4 v8 = *(float4*)&actT[row * WR + c * 8];
                const __half2* hp = (const __half2*)&v8;
                uint2 o;
                o.x = f16x4_to_fp8(hp[0], hp[1]);
                o.y = f16x4_to_fp8(hp[2], hp[3]);
                *(uint2*)&Hout[(size_t)(c >> 1) * psz + (size_t)grow * 16 + (c & 1) * 8] = o;
            }
        }
    }
}

// ---------------- final gather: 4 column planes, XCD-pinned ----------------
__global__ __launch_bounds__(256) void gather_out4(
    const int* __restrict__ off, const unsigned short* __restrict__ csr,
    const unsigned char* __restrict__ h3, int psz,
    const float* __restrict__ alS, const float* __restrict__ alD,
    const float* __restrict__ b, float* __restrict__ out, int n)
{
    const int g = blockIdx.x & 3;
    const int node = (blockIdx.x >> 2) * 256 + threadIdx.x;
    if (node >= n) return;
    const float ad = alD[node];
    const int s0 = off[node], s1 = off[node + 1];
    const int last = s1 - 1;
    const unsigned char* hp = h3 + (size_t)g * psz;

    float a[16];
#pragma unroll
    for (int i = 0; i < 16; i++) a[i] = 0.f;
    float wsum = 0.f;

    auto accum = [&](const uint4& vv, float w) {
        unsigned int dw[4] = { vv.x, vv.y, vv.z, vv.w };
#pragma unroll
        for (int d = 0; d < 4; d++) {
            f32x2 lo = __builtin_amdgcn_cvt_pk_f32_fp8(dw[d], false);
            f32x2 hi = __builtin_amdgcn_cvt_pk_f32_fp8(dw[d], true);
            a[d * 4 + 0] = fmaf(w, lo.x, a[d * 4 + 0]);
            a[d * 4 + 1] = fmaf(w, lo.y, a[d * 4 + 1]);
            a[d * 4 + 2] = fmaf(w, hi.x, a[d * 4 + 2]);
            a[d * 4 + 3] = fmaf(w, hi.y, a[d * 4 + 3]);
        }
        wsum += w;
    };

    int sA0 = csr[s0];
    int sA1 = csr[s0 + 1 <= last ? s0 + 1 : last];
    uint4 vA0 = *(const uint4*)(hp + sA0 * 16);
    uint4 vA1 = *(const uint4*)(hp + sA1 * 16);
    float aA0 = alS[sA0];
    float aA1 = alS[sA1];

    for (int j = s0; j < s1; j += 2) {
        int jn0 = j + 2 <= last ? j + 2 : last;
        int jn1 = j + 3 <= last ? j + 3 : last;
        int sB0 = csr[jn0], sB1 = csr[jn1];
        uint4 vB0 = *(const uint4*)(hp + sB0 * 16);
        uint4 vB1 = *(const uint4*)(hp + sB1 * 16);
        float aB0 = alS[sB0];
        float aB1 = alS[sB1];

        {
            float e = aA0 + ad; e = e > 0.f ? e : 0.2f * e;
            accum(vA0, __expf(e));
        }
        {
            float e = aA1 + ad; e = e > 0.f ? e : 0.2f * e;
            float w = (j + 1 <= last) ? __expf(e) : 0.f;
            accum(vA1, w);
        }
        sA0 = sB0; sA1 = sB1; vA0 = vB0; vA1 = vB1; aA0 = aB0; aA1 = aB1;
    }

    const float inv = 1.f / (wsum + 1e-16f);
    const int c0f = g * 16;
    float bb[16];
    *(float4*)&bb[0]  = *(const float4*)&b[c0f];
    *(float4*)&bb[4]  = *(const float4*)&b[c0f + 4];
    *(float4*)&bb[8]  = *(const float4*)&b[c0f + 8];
    *(float4*)&bb[12] = *(const float4*)&b[c0f + 12];
#pragma unroll
    for (int gq = 0; gq < 4; gq++) {
        float4 o;
        o.x = ELU(fmaf(a[4 * gq + 0], inv, bb[4 * gq + 0]));
        o.y = ELU(fmaf(a[4 * gq + 1], inv, bb[4 * gq + 1]));
        o.z = ELU(fmaf(a[4 * gq + 2], inv, bb[4 * gq + 2]));
        o.w = ELU(fmaf(a[4 * gq + 3], inv, bb[4 * gq + 3]));
        *(float4*)&out[(size_t)node * 64 + c0f + 4 * gq] = o;
    }
}

extern "C" void kernel_launch(void* const* d_in, const int* in_sizes, int n_in,
                              void* d_out, int out_size, void* d_ws, size_t ws_size,
                              hipStream_t stream)
{
    const float* x   = (const float*)d_in[0];
    const float* W1  = (const float*)d_in[1];
    const float* as1 = (const float*)d_in[2];
    const float* ad1 = (const float*)d_in[3];
    const float* b1  = (const float*)d_in[4];
    const float* W2  = (const float*)d_in[5];
    const float* as2 = (const float*)d_in[6];
    const float* ad2 = (const float*)d_in[7];
    const float* b2  = (const float*)d_in[8];
    const float* W3  = (const float*)d_in[9];
    const float* as3 = (const float*)d_in[10];
    const float* ad3 = (const float*)d_in[11];
    const float* b3  = (const float*)d_in[12];
    const int*   ei  = (const int*)d_in[13];
    float* out = (float*)d_out;

    const int N_   = in_sizes[0] / 128;     // 50000
    const int E_   = in_sizes[13] / 2;      // 1600000
    const int Etot = E_ + N_;
    const int NB   = (N_ + 255) >> BSH;     // 196 buckets
    const int HB   = (E_ + CHK - 1) / CHK;  // 196 hist/partition blocks
    const int np   = (N_ + 255) & ~255;     // padded node count (50176)
    const int psz  = np * 16;               // bytes per 16B h plane
    const int apsz = np * 32;               // bytes per 32B act plane

    char* ws = (char*)d_ws;
    size_t o = 0;
    auto alloc = [&](size_t bytes) { void* p = ws + o; o += (bytes + 255) & ~255ull; return p; };
    unsigned char* h1 = (unsigned char*)alloc((size_t)8 * psz);   // 8 planes
    unsigned char* h2 = (unsigned char*)alloc((size_t)8 * psz);
    unsigned char* h3 = (unsigned char*)alloc((size_t)4 * psz);
    __half* Wt1   = (__half*)alloc((size_t)128 * 128 * 2);
    __half* Wt2   = (__half*)alloc((size_t)128 * 128 * 2);
    __half* Wt3   = (__half*)alloc((size_t)64 * 128 * 2);
    float* alSa   = (float*)alloc((size_t)N_ * 2 * 4);
    float* alDa   = (float*)alloc((size_t)N_ * 2 * 4);
    float* alSb   = (float*)alloc((size_t)N_ * 2 * 4);
    float* alDb   = (float*)alloc((size_t)N_ * 2 * 4);
    int*   offb   = (int*)alloc((size_t)(N_ + 1) * 4);
    int*   bhrows = (int*)alloc((size_t)HB * 256 * 4);
    int*   boff   = (int*)alloc((size_t)257 * 4);
    int*   bases  = (int*)alloc((size_t)256 * HB * 4);
    unsigned short* csr = (unsigned short*)alloc((size_t)Etot * 2);
    // part (int, Etot) is dead after bucket_fill; act planes (ap) are only
    // written afterwards -> share one region.
    size_t shared_sz = (size_t)Etot * 4;
    size_t ap_sz = (size_t)8 * apsz;
    void* shared = alloc(shared_sz > ap_sz ? shared_sz : ap_sz);
    int* part = (int*)shared;
    unsigned char* ap = (unsigned char*)shared;

    const dim3 blk(256);

    // ---- CSR build (deterministic counting sort, no global atomics) ----
    phase0<<<160 + HB, blk, 0, stream>>>(W1, Wt1, W2, Wt2, W3, Wt3, ei, bhrows, E_);
    scan_bases<<<NB, blk, 0, stream>>>(bhrows, boff, bases, part, HB, N_, NB);
    edge_partition<<<HB, blk, 0, stream>>>(ei, bases, part, E_, HB, NB);
    bucket_fill<<<NB, blk, 0, stream>>>(boff, part, csr, offb, N_);

    // ---- layer pipeline ----
    gemm1_mfma<<<(N_ + 63) / 64, blk, 0, stream>>>(
        x, Wt1, h1, psz, as1, ad1, alSa, alDa, N_);
    gslice<<<((N_ + 255) / 256) * 8, blk, 0, stream>>>(
        offb, csr, h1, psz, alSa, alDa, b1, ap, apsz, N_);
    gemm_l<128><<<(N_ + 15) / 16, blk, 0, stream>>>(
        ap, apsz, Wt2, as2, ad2, h2, psz, alSb, alDb, N_);
    gslice<<<((N_ + 255) / 256) * 8, blk, 0, stream>>>(
        offb, csr, h2, psz, alSb, alDb, b2, ap, apsz, N_);
    gemm_l<64><<<(N_ + 15) / 16, blk, 0, stream>>>(
        ap, apsz, Wt3, as3, ad3, h3, psz, alSa, alDa, N_);
    gather_out4<<<((N_ + 255) / 256) * 4, blk, 0, stream>>>(
        offb, csr, h3, psz, alSa, alDa, b3, out, N_);
}

// Round 8
// 317.061 us; speedup vs baseline: 1.7001x; 1.7001x over previous
//
#include <hip/hip_runtime.h>
#include <hip/hip_bf16.h>
#include <hip/hip_fp16.h>

// ---------------------------------------------------------------------------
// 3-layer GAT encoder. N=50000, E=1600000 (+N self loops), H=2 (layers 1-2),
// F=64 per head, F_IN=128.
// R13: deterministic counting-sort CSR + fused gather/GEMM: 337us.
// R16: h fp8 e4m3, fused gather+GEMM: gg 52.5us/61.5MB FETCH, 294us. BEST.
// R17/R18 NEG: VALU/VMEM-count not binding. R19 FAILED: atomic scatter ->
//      107MB write-allocate. R20 FAILED: 8-way col slicing got FETCH
//      61.5->20MB (L2-residency mechanism PROVEN) but 1-lane/node serial
//      chain + 64-node/wave divergence -> 136us pure latency.
// R21: combine the proven halves. 2 column groups (64 cols, 3.2MB/plane
//      < 4MiB XCD L2), g = blockIdx&1 -> XCD parity pinning. Gather
//      microstructure = R16 exactly: 8 lanes/node, uint2, depth-4+4,
//      8 nodes/wave. gslice2 writes planar fp16 act; gemm_l (cheap in R20)
//      does act@Wt -> planar fp8 h + alS/alD. Final layer = R16 unsliced
//      gather_out (h3 3.2MB already L2-fits). csr ushort.
// ---------------------------------------------------------------------------

#define ELU(x) ((x) > 0.f ? (x) : (__expf(x) - 1.f))
#define BSH 8                       // 256 nodes per bucket
#define CHK 8192                    // edges per histogram/partition block

typedef _Float16 f16x8 __attribute__((ext_vector_type(8)));
typedef float    f32x4 __attribute__((ext_vector_type(4)));
typedef float    f32x2 __attribute__((ext_vector_type(2)));

// pack 4 f16 (as 2 half2) -> 4 fp8 e4m3 in one dword (RNE in HW)
__device__ inline unsigned int f16x4_to_fp8(__half2 h0, __half2 h1) {
    float2 a = __half22float2(h0), b = __half22float2(h1);
    unsigned int r = __builtin_amdgcn_cvt_pk_fp8_f32(a.x, a.y, 0, false);
    r = __builtin_amdgcn_cvt_pk_fp8_f32(b.x, b.y, r, true);
    return r;
}

// ---------------- phase0: Wt builds + per-block dst histogram rows ---------
__global__ __launch_bounds__(256) void phase0(
    const float* __restrict__ W1, __half* __restrict__ Wt1,
    const float* __restrict__ W2, __half* __restrict__ Wt2,
    const float* __restrict__ W3, __half* __restrict__ Wt3,
    const int* __restrict__ ei, int* __restrict__ bhist_rows, int E_)
{
    const int t = threadIdx.x;
    const int b = blockIdx.x;
    if (b < 160) {                                   // Wt[n][k] = (h) W[k][n]
        const float* W; __half* Wt; int N, base;
        if (b < 64)       { W = W1; Wt = Wt1; N = 128; base = b; }
        else if (b < 128) { W = W2; Wt = Wt2; N = 128; base = b - 64; }
        else              { W = W3; Wt = Wt3; N = 64;  base = b - 128; }
        int idx = base * 256 + t;
        if (idx < N * 128) {
            int nn = idx >> 7, k = idx & 127;
            Wt[idx] = __float2half(W[k * N + nn]);
        }
    } else {                                         // dst histogram row
        __shared__ int cnt[256];
        int hb = b - 160;
        cnt[t] = 0;
        __syncthreads();
        const int e0 = hb * CHK;
        for (int i = t; i < CHK; i += 256) {
            int e = e0 + i;
            if (e >= E_) break;
            atomicAdd(&cnt[ei[E_ + e] >> BSH], 1);
        }
        __syncthreads();
        bhist_rows[hb * 256 + t] = cnt[t];
    }
}

// one block per bucket: (a) bucket totals + scan (block 0 writes boff),
// (b) column scan of this bucket -> per-partition-block bases,
// (c) self-loop part entries at bucket tail. HB <= 256.
__global__ __launch_bounds__(256) void scan_bases(
    const int* __restrict__ bhist_rows, int* __restrict__ boff,
    int* __restrict__ bases, int* __restrict__ part, int HB, int n, int NB)
{
    __shared__ int tot[256];
    __shared__ int col[256];
    const int t = threadIdx.x;
    const int b = blockIdx.x;                        // bucket

    // bucket totals (+ self loops), inclusive scan
    int v = 0;
    for (int r = 0; r < HB; r++) v += bhist_rows[r * 256 + t];
    int nodes_t = n - (t << BSH);
    nodes_t = nodes_t < 0 ? 0 : (nodes_t > 256 ? 256 : nodes_t);
    v = (t < NB) ? (v + nodes_t) : 0;
    tot[t] = v;
    __syncthreads();
    for (int d = 1; d < 256; d <<= 1) {
        int x = (t >= d) ? tot[t - d] : 0;
        __syncthreads();
        tot[t] += x;
        __syncthreads();
    }
    if (b == 0) {
        if (t < NB) boff[t + 1] = tot[t];
        if (t == 0) boff[0] = 0;
    }
    const int base0 = (b > 0) ? tot[b - 1] : 0;      // boff[b]
    const int bend  = tot[b];                        // boff[b+1]

    // column scan for this bucket -> bases
    int c = (t < HB) ? bhist_rows[t * 256 + b] : 0;
    col[t] = c;
    __syncthreads();
    for (int d = 1; d < 256; d <<= 1) {
        int x = (t >= d) ? col[t - d] : 0;
        __syncthreads();
        col[t] += x;
        __syncthreads();
    }
    if (t < HB) bases[b * HB + t] = base0 + col[t] - c;   // exclusive

    // self loops at bucket tail (coalesced); src < 65536 fits low 16 bits
    const int n0 = b << BSH;
    const int nodes = min(256, n - n0);
    const int sl0 = bend - nodes;
    if (t < nodes) part[sl0 + t] = (n0 + t) | (t << 16);
}

// single-pass partition: deterministic bases, LDS-local cursors only.
// packed entry: src (bits 0..15) | dst_local (bits 16..23)
__global__ __launch_bounds__(256) void edge_partition(
    const int* __restrict__ ei, const int* __restrict__ bases,
    int* __restrict__ part, int E_, int HB, int NB)
{
    __shared__ int cnt[256];
    __shared__ int sbase[256];
    const int t = threadIdx.x;
    const int hb = blockIdx.x;
    cnt[t] = 0;
    sbase[t] = (t < NB) ? bases[t * HB + hb] : 0;
    __syncthreads();
    const int e0 = hb * CHK;
    for (int i = t; i < CHK; i += 256) {
        int e = e0 + i;
        if (e >= E_) break;
        int src = ei[e], dst = ei[E_ + e];
        int b = dst >> BSH;
        int pos = sbase[b] + atomicAdd(&cnt[b], 1);
        part[pos] = src | ((dst & 255) << 16);
    }
}

// one block per bucket: per-node degree count, LDS scan -> off[], place, flush
// csr output is ushort (src < 65536).
__global__ __launch_bounds__(256) void bucket_fill(
    const int* __restrict__ boff, const int* __restrict__ part,
    unsigned short* __restrict__ csr, int* __restrict__ off, int n)
{
    __shared__ int sm[256];
    __shared__ int cur[256];
    __shared__ int slice[12544];
    const int t = threadIdx.x;
    const int b = blockIdx.x;
    const int n0 = b << BSH;
    const int nodes = min(256, n - n0);
    const int off0 = boff[b];
    const int sz = boff[b + 1] - off0;

    cur[t] = 0;
    __syncthreads();
    for (int i = t; i < sz; i += 256)
        atomicAdd(&cur[(part[off0 + i] >> 16) & 255], 1);
    __syncthreads();
    int v = cur[t];
    sm[t] = v;
    __syncthreads();
    for (int d = 1; d < 256; d <<= 1) {
        int x = (t >= d) ? sm[t - d] : 0;
        __syncthreads();
        sm[t] += x;
        __syncthreads();
    }
    const int excl = sm[t] - v;
    if (t < nodes) off[n0 + t] = off0 + excl;
    if (t == nodes - 1) off[n0 + nodes] = off0 + sz;
    cur[t] = excl;
    __syncthreads();

    if (sz <= 12544) {
        for (int i = t; i < sz; i += 256) {
            int p  = part[off0 + i];
            int dl = (p >> 16) & 255;
            int pos = atomicAdd(&cur[dl], 1);
            slice[pos] = p & 0xFFFF;
        }
        __syncthreads();
        for (int i = t; i < sz; i += 256)
            csr[off0 + i] = (unsigned short)slice[i];
    } else {                                     // fallback (shouldn't trigger)
        for (int i = t; i < sz; i += 256) {
            int p  = part[off0 + i];
            int dl = (p >> 16) & 255;
            int pos = atomicAdd(&cur[dl], 1);
            csr[off0 + pos] = (unsigned short)(p & 0xFFFF);
        }
    }
}

// ---------------- layer-1 MFMA GEMM (fp32 A, LDS W) -> 2-plane fp8 h1 ------
// h plane g holds cols [g*64, g*64+64) as 64B rows.
__global__ __launch_bounds__(256) void gemm1_mfma(
    const float* __restrict__ A, const __half* __restrict__ Wt, // [128][128]
    unsigned char* __restrict__ Hout, int psz,
    const float* __restrict__ a_s, const float* __restrict__ a_d,
    float* __restrict__ alS, float* __restrict__ alD, int nrows)
{
    constexpr int N = 128, NT = 8, WR = 136;
    __shared__ _Float16 wt[N * WR];
    __shared__ _Float16 hst[4][16 * WR];

    const int t = threadIdx.x, w = t >> 6, l = t & 63;
    const int q = l >> 4, n = l & 15;
    const int node0 = blockIdx.x * 64;
    const int row_base = node0 + w * 16;

    for (int i = t; i < N * 16; i += 256) {
        int r = i >> 4, c = i & 15;
        float4 v = *(const float4*)&Wt[r * 128 + c * 8];
        *(float4*)&wt[r * WR + c * 8] = v;
    }
    __syncthreads();

    f32x4 acc[NT];
#pragma unroll
    for (int ct = 0; ct < NT; ct++) acc[ct] = (f32x4){0.f, 0.f, 0.f, 0.f};

    int arow = row_base + n; if (arow >= nrows) arow = nrows - 1;
    const float* Ap = A + (size_t)arow * 128 + q * 8;
#pragma unroll
    for (int ks = 0; ks < 4; ks++) {
        float4 va = *(const float4*)(Ap + ks * 32);
        float4 vb = *(const float4*)(Ap + ks * 32 + 4);
        f16x8 a = { (_Float16)va.x, (_Float16)va.y, (_Float16)va.z, (_Float16)va.w,
                    (_Float16)vb.x, (_Float16)vb.y, (_Float16)vb.z, (_Float16)vb.w };
#pragma unroll
        for (int ct = 0; ct < NT; ct++) {
            f16x8 bb = *(const f16x8*)&wt[(ct * 16 + n) * WR + ks * 32 + q * 8];
            acc[ct] = __builtin_amdgcn_mfma_f32_16x16x32_f16(a, bb, acc[ct], 0, 0, 0);
        }
    }

    float asv[NT], adv[NT];
#pragma unroll
    for (int ct = 0; ct < NT; ct++) {
        asv[ct] = a_s[ct * 16 + n];
        adv[ct] = a_d[ct * 16 + n];
    }
#pragma unroll
    for (int r = 0; r < 4; r++) {
        int grow = row_base + q * 4 + r;
        float s0 = 0.f, d0 = 0.f, s1 = 0.f, d1 = 0.f;
#pragma unroll
        for (int ct = 0; ct < NT; ct++) {
            float v = acc[ct][r];
            float ps = v * asv[ct], pd = v * adv[ct];
            if (ct >= 4) { s1 += ps; d1 += pd; }
            else         { s0 += ps; d0 += pd; }
        }
#pragma unroll
        for (int m = 1; m < 16; m <<= 1) {
            s0 += __shfl_xor(s0, m); d0 += __shfl_xor(d0, m);
            s1 += __shfl_xor(s1, m); d1 += __shfl_xor(d1, m);
        }
        if (n == 0 && grow < nrows) {
            alS[grow * 2] = s0;     alD[grow * 2] = d0;
            alS[grow * 2 + 1] = s1; alD[grow * 2 + 1] = d1;
        }
    }

#pragma unroll
    for (int ct = 0; ct < NT; ct++)
#pragma unroll
        for (int r = 0; r < 4; r++)
            hst[w][(q * 4 + r) * WR + ct * 16 + n] = (_Float16)acc[ct][r];
    __syncthreads();
    {
        int row = l >> 2, c = l & 3;            // 4 lanes x 32 cols
        int grow = row_base + row;
        if (grow < nrows) {
#pragma unroll
            for (int i = 0; i < 4; i++) {
                float4 v = *(float4*)&hst[w][row * WR + c * 32 + i * 8];
                const __half2* hp = (const __half2*)&v;
                uint2 o;
                o.x = f16x4_to_fp8(hp[0], hp[1]);
                o.y = f16x4_to_fp8(hp[2], hp[3]);
                int cb = c * 32 + i * 8;        // byte col 0..127
                *(uint2*)&Hout[(size_t)(cb >> 6) * psz + (size_t)grow * 64 + (cb & 63)] = o;
            }
        }
    }
}

// ---------------- gslice2: XCD-parity column-half gather -------------------
// g = blockIdx&1 (-> XCD parity). Plane g = 64 fp8 cols (3.2MB, L2-fits).
// R16 microstructure: 8 lanes/node, uint2, depth-4+4, 32 nodes/block.
// Writes planar fp16 act: ap[g][node][128B].
__global__ __launch_bounds__(256) void gslice2(
    const int* __restrict__ off, const unsigned short* __restrict__ csr,
    const unsigned char* __restrict__ h, int psz,
    const float* __restrict__ alS, const float* __restrict__ alD,
    const float* __restrict__ bias, unsigned char* __restrict__ ap,
    int apsz, int n)
{
    const int g = blockIdx.x & 1;
    const int t = threadIdx.x;
    const int l = t & 7;
    const int node = (blockIdx.x >> 1) * 32 + (t >> 3);
    const bool valid = node < n;
    const int c0 = l * 8;                 // within-plane byte col
    const int nodec = valid ? node : (n - 1);
    const float ad = alD[nodec * 2 + g];
    int s0 = 0, s1 = 1;
    if (valid) { s0 = off[node]; s1 = off[node + 1]; }
    const int last = s1 - 1;
    const unsigned char* hp = h + (size_t)g * psz;

    float a0 = 0.f, a1 = 0.f, a2 = 0.f, a3 = 0.f;
    float a4 = 0.f, a5 = 0.f, a6 = 0.f, a7 = 0.f, wsum = 0.f;

    float as[4];
    uint2 v[4];
    {
        int srcs[4];
#pragma unroll
        for (int k = 0; k < 4; k++) {
            int j = s0 + k;
            srcs[k] = csr[j <= last ? j : last];
        }
#pragma unroll
        for (int k = 0; k < 4; k++) {
            as[k] = alS[srcs[k] * 2 + g];
            v[k]  = *(const uint2*)&hp[(size_t)srcs[k] * 64 + c0];
        }
    }
    for (int j = s0; j < s1; j += 4) {
        int nsrc[4];
#pragma unroll
        for (int k = 0; k < 4; k++) {
            int jj = j + 4 + k;
            nsrc[k] = csr[jj <= last ? jj : last];
        }
        float nas[4];
        uint2 nv[4];
#pragma unroll
        for (int k = 0; k < 4; k++) {
            nas[k] = alS[nsrc[k] * 2 + g];
            nv[k]  = *(const uint2*)&hp[(size_t)nsrc[k] * 64 + c0];
        }
#pragma unroll
        for (int k = 0; k < 4; k++) {
            float s = as[k] + ad;
            s = s > 0.f ? s : 0.2f * s;     // leaky_relu(0.2)
            float w = __expf(s);
            w = (j + k <= last) ? w : 0.f;
            f32x2 f0 = __builtin_amdgcn_cvt_pk_f32_fp8(v[k].x, false);
            f32x2 f1 = __builtin_amdgcn_cvt_pk_f32_fp8(v[k].x, true);
            f32x2 f2 = __builtin_amdgcn_cvt_pk_f32_fp8(v[k].y, false);
            f32x2 f3 = __builtin_amdgcn_cvt_pk_f32_fp8(v[k].y, true);
            a0 = fmaf(w, f0.x, a0); a1 = fmaf(w, f0.y, a1);
            a2 = fmaf(w, f1.x, a2); a3 = fmaf(w, f1.y, a3);
            a4 = fmaf(w, f2.x, a4); a5 = fmaf(w, f2.y, a5);
            a6 = fmaf(w, f3.x, a6); a7 = fmaf(w, f3.y, a7);
            wsum += w;
        }
#pragma unroll
        for (int k = 0; k < 4; k++) { as[k] = nas[k]; v[k] = nv[k]; }
    }
    if (valid) {
        const float inv = 1.f / (wsum + 1e-16f);
        const int cf = g * 64 + c0;           // fp32 col
        float4 b0 = *(const float4*)&bias[cf];
        float4 b1 = *(const float4*)&bias[cf + 4];
        float o[8];
        o[0] = ELU(fmaf(a0, inv, b0.x));
        o[1] = ELU(fmaf(a1, inv, b0.y));
        o[2] = ELU(fmaf(a2, inv, b0.z));
        o[3] = ELU(fmaf(a3, inv, b0.w));
        o[4] = ELU(fmaf(a4, inv, b1.x));
        o[5] = ELU(fmaf(a5, inv, b1.y));
        o[6] = ELU(fmaf(a6, inv, b1.z));
        o[7] = ELU(fmaf(a7, inv, b1.w));
        __half2 p[4];
#pragma unroll
        for (int k = 0; k < 4; k++) p[k] = __floats2half2_rn(o[2 * k], o[2 * k + 1]);
        *(float4*)&ap[(size_t)g * apsz + (size_t)node * 128 + l * 16] = *(float4*)p;
    }
}

// ---------------- gemm_l: planar fp16 act -> MFMA -> fp8 h + alS -----------
// OUTN=128: Hout 2-plane 64B rows. OUTN=64: Hout row-major 64B rows.
template<int OUTN>
__global__ __launch_bounds__(256) void gemm_l(
    const unsigned char* __restrict__ ap, int apsz,
    const __half* __restrict__ Wt, const float* __restrict__ a_s,
    const float* __restrict__ a_d, unsigned char* __restrict__ Hout,
    int psz, float* __restrict__ alSo, float* __restrict__ alDo, int n)
{
    constexpr int WR = 136;
    constexpr int CTW = OUTN / 64;        // col-tiles per wave
    constexpr int CPW = OUTN / 4;         // cols per wave
    __shared__ _Float16 actT[16 * WR];
    __shared__ float red_s[4][16], red_d[4][16];

    const int t = threadIdx.x;
    const int node0 = blockIdx.x * 16;

    {   // stage 16 act rows (2 planes x 128B) -> LDS
        int row = t >> 4, c = t & 15;      // 16B chunk
        int grow = node0 + row; if (grow >= n) grow = n - 1;
        int cb2 = c * 16;                  // byte offset in 256B logical row
        int pl = cb2 >> 7, o2 = cb2 & 127;
        float4 v = *(const float4*)(ap + (size_t)pl * apsz + (size_t)grow * 128 + o2);
        *(float4*)&actT[row * WR + c * 8] = v;
    }
    __syncthreads();

    const int w = t >> 6, l64 = t & 63, q = l64 >> 4, nn = l64 & 15;
    const __half* Wp = Wt + (size_t)(w * CPW + nn) * 128 + q * 8;
    f32x4 acc[CTW];
#pragma unroll
    for (int ct = 0; ct < CTW; ct++) acc[ct] = (f32x4){0.f, 0.f, 0.f, 0.f};
#pragma unroll
    for (int ks = 0; ks < 4; ks++) {
        f16x8 a = *(const f16x8*)&actT[nn * WR + ks * 32 + q * 8];
#pragma unroll
        for (int ct = 0; ct < CTW; ct++) {
            f16x8 bb = *(const f16x8*)(Wp + ct * 16 * 128 + ks * 32);
            acc[ct] = __builtin_amdgcn_mfma_f32_16x16x32_f16(a, bb, acc[ct], 0, 0, 0);
        }
    }

    float asv[CTW], adv2[CTW];
#pragma unroll
    for (int ct = 0; ct < CTW; ct++) {
        asv[ct]  = a_s[w * CPW + ct * 16 + nn];
        adv2[ct] = a_d[w * CPW + ct * 16 + nn];
    }
#pragma unroll
    for (int r = 0; r < 4; r++) {
        float s = 0.f, d = 0.f;
#pragma unroll
        for (int ct = 0; ct < CTW; ct++) {
            float vv = acc[ct][r];
            s = fmaf(vv, asv[ct], s);
            d = fmaf(vv, adv2[ct], d);
        }
#pragma unroll
        for (int m = 1; m < 16; m <<= 1) {
            s += __shfl_xor(s, m);
            d += __shfl_xor(d, m);
        }
        if (nn == 0) { red_s[w][q * 4 + r] = s; red_d[w][q * 4 + r] = d; }
    }
    __syncthreads();

    // stage output into actT (reuse)
#pragma unroll
    for (int ct = 0; ct < CTW; ct++)
#pragma unroll
        for (int r = 0; r < 4; r++)
            actT[(q * 4 + r) * WR + w * CPW + ct * 16 + nn] = (_Float16)acc[ct][r];
    if (OUTN == 128) {
        if (t < 32) {
            int m = t & 15, hh = t >> 4;
            int grow = node0 + m;
            if (grow < n) {
                alSo[grow * 2 + hh] = red_s[2 * hh][m] + red_s[2 * hh + 1][m];
                alDo[grow * 2 + hh] = red_d[2 * hh][m] + red_d[2 * hh + 1][m];
            }
        }
    } else {
        if (t < 16) {
            int grow = node0 + t;
            if (grow < n) {
                alSo[grow] = red_s[0][t] + red_s[1][t] + red_s[2][t] + red_s[3][t];
                alDo[grow] = red_d[0][t] + red_d[1][t] + red_d[2][t] + red_d[3][t];
            }
        }
    }
    __syncthreads();

    // fp8 Hout store
    if (OUTN == 128) {
        int row = t >> 4, c = t & 15;          // byte col cb = c*8
        int grow = node0 + row;
        if (grow < n) {
            float4 v8 = *(float4*)&actT[row * WR + c * 8];
            const __half2* hp = (const __half2*)&v8;
            uint2 o;
            o.x = f16x4_to_fp8(hp[0], hp[1]);
            o.y = f16x4_to_fp8(hp[2], hp[3]);
            int cb = c * 8;
            *(uint2*)&Hout[(size_t)(cb >> 6) * psz + (size_t)grow * 64 + (cb & 63)] = o;
        }
    } else {
        if (t < 128) {
            int row = t >> 3, c = t & 7;       // row-major 64B rows
            int grow = node0 + row;
            if (grow < n) {
                float4 v8 = *(float4*)&actT[row * WR + c * 8];
                const __half2* hp = (const __half2*)&v8;
                uint2 o;
                o.x = f16x4_to_fp8(hp[0], hp[1]);
                o.y = f16x4_to_fp8(hp[2], hp[3]);
                *(uint2*)&Hout[(size_t)grow * 64 + c * 8] = o;
            }
        }
    }
}

// ---------------- final gather (H=1, fp8 h row-major) -> fp32 out ----------
// R16 config: 8 lanes x uint2, 32 nodes/block, depth-4+4 prefetch.
__global__ __launch_bounds__(256) void gat_gather_out(
    const int* __restrict__ off, const unsigned short* __restrict__ csr,
    const unsigned char* __restrict__ h, const float* __restrict__ alS,
    const float* __restrict__ alD, const float* __restrict__ b,
    float* __restrict__ out, int n)
{
    constexpr int HF = 64, LPN = 8, NPB = 32;   // HF in BYTES (fp8)
    const int l    = threadIdx.x % LPN;
    const int node = blockIdx.x * NPB + threadIdx.x / LPN;
    if (node >= n) return;
    const int c0   = l * 8;
    const float ad = alD[node];

    const int s0 = off[node], s1 = off[node + 1];
    const int last = s1 - 1;
    float a0 = 0.f, a1 = 0.f, a2 = 0.f, a3 = 0.f;
    float a4 = 0.f, a5 = 0.f, a6 = 0.f, a7 = 0.f, wsum = 0.f;

    float as[4];
    uint2 v[4];
    {
        int srcs[4];
#pragma unroll
        for (int k = 0; k < 4; k++) {
            int j = s0 + k;
            srcs[k] = csr[j <= last ? j : last];
        }
#pragma unroll
        for (int k = 0; k < 4; k++) {
            as[k] = alS[srcs[k]];
            v[k]  = *(const uint2*)&h[(size_t)srcs[k] * HF + c0];
        }
    }
    for (int j = s0; j < s1; j += 4) {
        int nsrc[4];
#pragma unroll
        for (int k = 0; k < 4; k++) {
            int jj = j + 4 + k;
            nsrc[k] = csr[jj <= last ? jj : last];
        }
        float nas[4];
        uint2 nv[4];
#pragma unroll
        for (int k = 0; k < 4; k++) {
            nas[k] = alS[nsrc[k]];
            nv[k]  = *(const uint2*)&h[(size_t)nsrc[k] * HF + c0];
        }
#pragma unroll
        for (int k = 0; k < 4; k++) {
            float s = as[k] + ad;
            s = s > 0.f ? s : 0.2f * s;
            float w = __expf(s);
            w = (j + k <= last) ? w : 0.f;
            f32x2 f0 = __builtin_amdgcn_cvt_pk_f32_fp8(v[k].x, false);
            f32x2 f1 = __builtin_amdgcn_cvt_pk_f32_fp8(v[k].x, true);
            f32x2 f2 = __builtin_amdgcn_cvt_pk_f32_fp8(v[k].y, false);
            f32x2 f3 = __builtin_amdgcn_cvt_pk_f32_fp8(v[k].y, true);
            a0 = fmaf(w, f0.x, a0); a1 = fmaf(w, f0.y, a1);
            a2 = fmaf(w, f1.x, a2); a3 = fmaf(w, f1.y, a3);
            a4 = fmaf(w, f2.x, a4); a5 = fmaf(w, f2.y, a5);
            a6 = fmaf(w, f3.x, a6); a7 = fmaf(w, f3.y, a7);
            wsum += w;
        }
#pragma unroll
        for (int k = 0; k < 4; k++) { as[k] = nas[k]; v[k] = nv[k]; }
    }

    const float inv = 1.f / (wsum + 1e-16f);
    float4 b0 = *(const float4*)&b[c0];
    float4 b1 = *(const float4*)&b[c0 + 4];
    float4 o0, o1;
    o0.x = ELU(fmaf(a0, inv, b0.x));
    o0.y = ELU(fmaf(a1, inv, b0.y));
    o0.z = ELU(fmaf(a2, inv, b0.z));
    o0.w = ELU(fmaf(a3, inv, b0.w));
    o1.x = ELU(fmaf(a4, inv, b1.x));
    o1.y = ELU(fmaf(a5, inv, b1.y));
    o1.z = ELU(fmaf(a6, inv, b1.z));
    o1.w = ELU(fmaf(a7, inv, b1.w));
    *(float4*)&out[(size_t)node * HF + c0]     = o0;
    *(float4*)&out[(size_t)node * HF + c0 + 4] = o1;
}

extern "C" void kernel_launch(void* const* d_in, const int* in_sizes, int n_in,
                              void* d_out, int out_size, void* d_ws, size_t ws_size,
                              hipStream_t stream)
{
    const float* x   = (const float*)d_in[0];
    const float* W1  = (const float*)d_in[1];
    const float* as1 = (const float*)d_in[2];
    const float* ad1 = (const float*)d_in[3];
    const float* b1  = (const float*)d_in[4];
    const float* W2  = (const float*)d_in[5];
    const float* as2 = (const float*)d_in[6];
    const float* ad2 = (const float*)d_in[7];
    const float* b2  = (const float*)d_in[8];
    const float* W3  = (const float*)d_in[9];
    const float* as3 = (const float*)d_in[10];
    const float* ad3 = (const float*)d_in[11];
    const float* b3  = (const float*)d_in[12];
    const int*   ei  = (const int*)d_in[13];
    float* out = (float*)d_out;

    const int N_   = in_sizes[0] / 128;     // 50000
    const int E_   = in_sizes[13] / 2;      // 1600000
    const int Etot = E_ + N_;
    const int NB   = (N_ + 255) >> BSH;     // 196 buckets
    const int HB   = (E_ + CHK - 1) / CHK;  // 196 hist/partition blocks
    const int np   = (N_ + 255) & ~255;     // padded node count (50176)
    const int psz  = np * 64;               // bytes per 64-col fp8 h plane
    const int apsz = np * 128;              // bytes per 64-col fp16 act plane

    char* ws = (char*)d_ws;
    size_t o = 0;
    auto alloc = [&](size_t bytes) { void* p = ws + o; o += (bytes + 255) & ~255ull; return p; };
    unsigned char* h1 = (unsigned char*)alloc((size_t)2 * psz);   // 2 planes
    unsigned char* h2 = (unsigned char*)alloc((size_t)2 * psz);
    unsigned char* h3 = (unsigned char*)alloc((size_t)psz);       // row-major
    __half* Wt1   = (__half*)alloc((size_t)128 * 128 * 2);
    __half* Wt2   = (__half*)alloc((size_t)128 * 128 * 2);
    __half* Wt3   = (__half*)alloc((size_t)64 * 128 * 2);
    float* alSa   = (float*)alloc((size_t)N_ * 2 * 4);
    float* alDa   = (float*)alloc((size_t)N_ * 2 * 4);
    float* alSb   = (float*)alloc((size_t)N_ * 2 * 4);
    float* alDb   = (float*)alloc((size_t)N_ * 2 * 4);
    int*   offb   = (int*)alloc((size_t)(N_ + 1) * 4);
    int*   bhrows = (int*)alloc((size_t)HB * 256 * 4);
    int*   boff   = (int*)alloc((size_t)257 * 4);
    int*   bases  = (int*)alloc((size_t)256 * HB * 4);
    unsigned short* csr = (unsigned short*)alloc((size_t)Etot * 2);
    // part (int, Etot) dead after bucket_fill; act planes used afterwards.
    size_t part_sz = (size_t)Etot * 4;
    size_t ap_sz   = (size_t)2 * apsz;
    void* shared = alloc(part_sz > ap_sz ? part_sz : ap_sz);
    int* part = (int*)shared;
    unsigned char* ap = (unsigned char*)shared;

    const dim3 blk(256);

    // ---- CSR build (deterministic counting sort, no global atomics) ----
    phase0<<<160 + HB, blk, 0, stream>>>(W1, Wt1, W2, Wt2, W3, Wt3, ei, bhrows, E_);
    scan_bases<<<NB, blk, 0, stream>>>(bhrows, boff, bases, part, HB, N_, NB);
    edge_partition<<<HB, blk, 0, stream>>>(ei, bases, part, E_, HB, NB);
    bucket_fill<<<NB, blk, 0, stream>>>(boff, part, csr, offb, N_);

    // ---- layer pipeline ----
    gemm1_mfma<<<(N_ + 63) / 64, blk, 0, stream>>>(
        x, Wt1, h1, psz, as1, ad1, alSa, alDa, N_);
    gslice2<<<((N_ + 31) / 32) * 2, blk, 0, stream>>>(
        offb, csr, h1, psz, alSa, alDa, b1, ap, apsz, N_);
    gemm_l<128><<<(N_ + 15) / 16, blk, 0, stream>>>(
        ap, apsz, Wt2, as2, ad2, h2, psz, alSb, alDb, N_);
    gslice2<<<((N_ + 31) / 32) * 2, blk, 0, stream>>>(
        offb, csr, h2, psz, alSb, alDb, b2, ap, apsz, N_);
    gemm_l<64><<<(N_ + 15) / 16, blk, 0, stream>>>(
        ap, apsz, Wt3, as3, ad3, h3, psz, alSa, alDa, N_);
    gat_gather_out<<<(N_ + 31) / 32, blk, 0, stream>>>(
        offb, csr, h3, alSa, alDa, b3, out, N_);
}

// Round 9
// 288.444 us; speedup vs baseline: 1.8688x; 1.0992x over previous
//
#include <hip/hip_runtime.h>
#include <hip/hip_bf16.h>
#include <hip/hip_fp16.h>

// ---------------------------------------------------------------------------
// 3-layer GAT encoder. N=50000, E=1600000 (+N self loops), H=2 (layers 1-2),
// F=64 per head, F_IN=128.
// R13: deterministic counting-sort CSR + fused gather/GEMM: 337us.
// R16: h fp8 e4m3, fused gather+GEMM: gg 52.5us/61.5MB FETCH, 294us. BEST.
// R17 NEG: shfl meta dedup -> DS on critical path. R18 NEG: 8-lane uint4.
// R19 FAILED: atomic scatter -> 107MB write-allocate.
// R20/R21: column-plane L2 pinning works (FETCH 61.5->27.8MB, gslice2
//      47.9us) but un-fusing the GEMM costs more than the win (317us).
// R22: keep R16 fused structure; de-replicate per-edge metadata via LDS.
//      Phase A: 256 threads sweep the block's CONTIGUOUS csr span
//      (coalesced ushort), binary-search dst in 17-entry LDS off table,
//      compute w=exp(leaky(alS+alD)) ONCE per edge -> LDS {src,w0,w1}.
//      Phase B: R16 depth-4+4 pipelined gather, meta from LDS broadcast
//      (16 lanes same slot = conflict-free). Per edge-lane: 3 VMEM -> 1,
//      ~20 VALU -> ~14. Chunked (C=768) for correctness at any degree.
//      Same for gat_gather_out (32 nodes, C=1280). csr ushort.
// ---------------------------------------------------------------------------

#define ELU(x) ((x) > 0.f ? (x) : (__expf(x) - 1.f))
#define BSH 8                       // 256 nodes per bucket
#define CHK 8192                    // edges per histogram/partition block

typedef _Float16 f16x8 __attribute__((ext_vector_type(8)));
typedef float    f32x4 __attribute__((ext_vector_type(4)));
typedef float    f32x2 __attribute__((ext_vector_type(2)));

// pack 4 f16 (as 2 half2) -> 4 fp8 e4m3 in one dword (RNE in HW)
__device__ inline unsigned int f16x4_to_fp8(__half2 h0, __half2 h1) {
    float2 a = __half22float2(h0), b = __half22float2(h1);
    unsigned int r = __builtin_amdgcn_cvt_pk_fp8_f32(a.x, a.y, 0, false);
    r = __builtin_amdgcn_cvt_pk_fp8_f32(b.x, b.y, r, true);
    return r;
}

// ---------------- phase0: Wt builds + per-block dst histogram rows ---------
__global__ __launch_bounds__(256) void phase0(
    const float* __restrict__ W1, __half* __restrict__ Wt1,
    const float* __restrict__ W2, __half* __restrict__ Wt2,
    const float* __restrict__ W3, __half* __restrict__ Wt3,
    const int* __restrict__ ei, int* __restrict__ bhist_rows, int E_)
{
    const int t = threadIdx.x;
    const int b = blockIdx.x;
    if (b < 160) {                                   // Wt[n][k] = (h) W[k][n]
        const float* W; __half* Wt; int N, base;
        if (b < 64)       { W = W1; Wt = Wt1; N = 128; base = b; }
        else if (b < 128) { W = W2; Wt = Wt2; N = 128; base = b - 64; }
        else              { W = W3; Wt = Wt3; N = 64;  base = b - 128; }
        int idx = base * 256 + t;
        if (idx < N * 128) {
            int nn = idx >> 7, k = idx & 127;
            Wt[idx] = __float2half(W[k * N + nn]);
        }
    } else {                                         // dst histogram row
        __shared__ int cnt[256];
        int hb = b - 160;
        cnt[t] = 0;
        __syncthreads();
        const int e0 = hb * CHK;
        for (int i = t; i < CHK; i += 256) {
            int e = e0 + i;
            if (e >= E_) break;
            atomicAdd(&cnt[ei[E_ + e] >> BSH], 1);
        }
        __syncthreads();
        bhist_rows[hb * 256 + t] = cnt[t];
    }
}

// one block per bucket: (a) bucket totals + scan (block 0 writes boff),
// (b) column scan of this bucket -> per-partition-block bases,
// (c) self-loop part entries at bucket tail. HB <= 256.
__global__ __launch_bounds__(256) void scan_bases(
    const int* __restrict__ bhist_rows, int* __restrict__ boff,
    int* __restrict__ bases, int* __restrict__ part, int HB, int n, int NB)
{
    __shared__ int tot[256];
    __shared__ int col[256];
    const int t = threadIdx.x;
    const int b = blockIdx.x;                        // bucket

    // bucket totals (+ self loops), inclusive scan
    int v = 0;
    for (int r = 0; r < HB; r++) v += bhist_rows[r * 256 + t];
    int nodes_t = n - (t << BSH);
    nodes_t = nodes_t < 0 ? 0 : (nodes_t > 256 ? 256 : nodes_t);
    v = (t < NB) ? (v + nodes_t) : 0;
    tot[t] = v;
    __syncthreads();
    for (int d = 1; d < 256; d <<= 1) {
        int x = (t >= d) ? tot[t - d] : 0;
        __syncthreads();
        tot[t] += x;
        __syncthreads();
    }
    if (b == 0) {
        if (t < NB) boff[t + 1] = tot[t];
        if (t == 0) boff[0] = 0;
    }
    const int base0 = (b > 0) ? tot[b - 1] : 0;      // boff[b]
    const int bend  = tot[b];                        // boff[b+1]

    // column scan for this bucket -> bases
    int c = (t < HB) ? bhist_rows[t * 256 + b] : 0;
    col[t] = c;
    __syncthreads();
    for (int d = 1; d < 256; d <<= 1) {
        int x = (t >= d) ? col[t - d] : 0;
        __syncthreads();
        col[t] += x;
        __syncthreads();
    }
    if (t < HB) bases[b * HB + t] = base0 + col[t] - c;   // exclusive

    // self loops at bucket tail (coalesced); src < 65536 fits low 16 bits
    const int n0 = b << BSH;
    const int nodes = min(256, n - n0);
    const int sl0 = bend - nodes;
    if (t < nodes) part[sl0 + t] = (n0 + t) | (t << 16);
}

// single-pass partition: deterministic bases, LDS-local cursors only.
// packed entry: src (bits 0..15) | dst_local (bits 16..23)
__global__ __launch_bounds__(256) void edge_partition(
    const int* __restrict__ ei, const int* __restrict__ bases,
    int* __restrict__ part, int E_, int HB, int NB)
{
    __shared__ int cnt[256];
    __shared__ int sbase[256];
    const int t = threadIdx.x;
    const int hb = blockIdx.x;
    cnt[t] = 0;
    sbase[t] = (t < NB) ? bases[t * HB + hb] : 0;
    __syncthreads();
    const int e0 = hb * CHK;
    for (int i = t; i < CHK; i += 256) {
        int e = e0 + i;
        if (e >= E_) break;
        int src = ei[e], dst = ei[E_ + e];
        int b = dst >> BSH;
        int pos = sbase[b] + atomicAdd(&cnt[b], 1);
        part[pos] = src | ((dst & 255) << 16);
    }
}

// one block per bucket: per-node degree count, LDS scan -> off[], place, flush
// csr output is ushort (src < 65536).
__global__ __launch_bounds__(256) void bucket_fill(
    const int* __restrict__ boff, const int* __restrict__ part,
    unsigned short* __restrict__ csr, int* __restrict__ off, int n)
{
    __shared__ int sm[256];
    __shared__ int cur[256];
    __shared__ int slice[12544];
    const int t = threadIdx.x;
    const int b = blockIdx.x;
    const int n0 = b << BSH;
    const int nodes = min(256, n - n0);
    const int off0 = boff[b];
    const int sz = boff[b + 1] - off0;

    cur[t] = 0;
    __syncthreads();
    for (int i = t; i < sz; i += 256)
        atomicAdd(&cur[(part[off0 + i] >> 16) & 255], 1);
    __syncthreads();
    int v = cur[t];
    sm[t] = v;
    __syncthreads();
    for (int d = 1; d < 256; d <<= 1) {
        int x = (t >= d) ? sm[t - d] : 0;
        __syncthreads();
        sm[t] += x;
        __syncthreads();
    }
    const int excl = sm[t] - v;
    if (t < nodes) off[n0 + t] = off0 + excl;
    if (t == nodes - 1) off[n0 + nodes] = off0 + sz;
    cur[t] = excl;
    __syncthreads();

    if (sz <= 12544) {
        for (int i = t; i < sz; i += 256) {
            int p  = part[off0 + i];
            int dl = (p >> 16) & 255;
            int pos = atomicAdd(&cur[dl], 1);
            slice[pos] = p & 0xFFFF;
        }
        __syncthreads();
        for (int i = t; i < sz; i += 256)
            csr[off0 + i] = (unsigned short)slice[i];
    } else {                                     // fallback (shouldn't trigger)
        for (int i = t; i < sz; i += 256) {
            int p  = part[off0 + i];
            int dl = (p >> 16) & 255;
            int pos = atomicAdd(&cur[dl], 1);
            csr[off0 + pos] = (unsigned short)(p & 0xFFFF);
        }
    }
}

// ---------------- layer-1 MFMA GEMM (fp32 A, LDS W) -> fp8 h1 (128B rows) --
__global__ __launch_bounds__(256) void gemm1_mfma(
    const float* __restrict__ A, const __half* __restrict__ Wt, // [128][128]
    unsigned char* __restrict__ Hout, const float* __restrict__ a_s,
    const float* __restrict__ a_d, float* __restrict__ alS,
    float* __restrict__ alD, int nrows)
{
    constexpr int N = 128, NT = 8, WR = 136;
    __shared__ _Float16 wt[N * WR];
    __shared__ _Float16 hst[4][16 * WR];

    const int t = threadIdx.x, w = t >> 6, l = t & 63;
    const int q = l >> 4, n = l & 15;
    const int node0 = blockIdx.x * 64;
    const int row_base = node0 + w * 16;

    for (int i = t; i < N * 16; i += 256) {
        int r = i >> 4, c = i & 15;
        float4 v = *(const float4*)&Wt[r * 128 + c * 8];
        *(float4*)&wt[r * WR + c * 8] = v;
    }
    __syncthreads();

    f32x4 acc[NT];
#pragma unroll
    for (int ct = 0; ct < NT; ct++) acc[ct] = (f32x4){0.f, 0.f, 0.f, 0.f};

    int arow = row_base + n; if (arow >= nrows) arow = nrows - 1;
    const float* Ap = A + (size_t)arow * 128 + q * 8;
#pragma unroll
    for (int ks = 0; ks < 4; ks++) {
        float4 va = *(const float4*)(Ap + ks * 32);
        float4 vb = *(const float4*)(Ap + ks * 32 + 4);
        f16x8 a = { (_Float16)va.x, (_Float16)va.y, (_Float16)va.z, (_Float16)va.w,
                    (_Float16)vb.x, (_Float16)vb.y, (_Float16)vb.z, (_Float16)vb.w };
#pragma unroll
        for (int ct = 0; ct < NT; ct++) {
            f16x8 bb = *(const f16x8*)&wt[(ct * 16 + n) * WR + ks * 32 + q * 8];
            acc[ct] = __builtin_amdgcn_mfma_f32_16x16x32_f16(a, bb, acc[ct], 0, 0, 0);
        }
    }

    float asv[NT], adv[NT];
#pragma unroll
    for (int ct = 0; ct < NT; ct++) {
        asv[ct] = a_s[ct * 16 + n];
        adv[ct] = a_d[ct * 16 + n];
    }
#pragma unroll
    for (int r = 0; r < 4; r++) {
        int grow = row_base + q * 4 + r;
        float s0 = 0.f, d0 = 0.f, s1 = 0.f, d1 = 0.f;
#pragma unroll
        for (int ct = 0; ct < NT; ct++) {
            float v = acc[ct][r];
            float ps = v * asv[ct], pd = v * adv[ct];
            if (ct >= 4) { s1 += ps; d1 += pd; }
            else         { s0 += ps; d0 += pd; }
        }
#pragma unroll
        for (int m = 1; m < 16; m <<= 1) {
            s0 += __shfl_xor(s0, m); d0 += __shfl_xor(d0, m);
            s1 += __shfl_xor(s1, m); d1 += __shfl_xor(d1, m);
        }
        if (n == 0 && grow < nrows) {
            alS[grow * 2] = s0;     alD[grow * 2] = d0;
            alS[grow * 2 + 1] = s1; alD[grow * 2 + 1] = d1;
        }
    }

#pragma unroll
    for (int ct = 0; ct < NT; ct++)
#pragma unroll
        for (int r = 0; r < 4; r++)
            hst[w][(q * 4 + r) * WR + ct * 16 + n] = (_Float16)acc[ct][r];
    __syncthreads();
    {
        int row = l >> 2, c = l & 3;            // 4 lanes x 32 cols
        int grow = row_base + row;
        if (grow < nrows) {
#pragma unroll
            for (int i = 0; i < 4; i++) {
                float4 v = *(float4*)&hst[w][row * WR + c * 32 + i * 8];
                const __half2* hp = (const __half2*)&v;
                uint2 o;
                o.x = f16x4_to_fp8(hp[0], hp[1]);
                o.y = f16x4_to_fp8(hp[2], hp[3]);
                *(uint2*)&Hout[(size_t)grow * 128 + c * 32 + i * 8] = o;
            }
        }
    }
}

// ---------------- fused gather (H=2) + next-layer GEMM ---------------------
// R22: phase A computes per-edge meta once into LDS; phase B = R16 depth-4+4
// pipelined gather with LDS-broadcast meta. Fused GEMM epilogue unchanged.
template<int OUTN>
__global__ __launch_bounds__(256) void gat_gather_gemm(
    const int* __restrict__ off, const unsigned short* __restrict__ csr,
    const unsigned char* __restrict__ h, const float* __restrict__ alS,
    const float* __restrict__ alD, const float* __restrict__ bias,
    const __half* __restrict__ Wt, const float* __restrict__ a_s,
    const float* __restrict__ a_d, unsigned char* __restrict__ Hout,
    float* __restrict__ alSo, float* __restrict__ alDo, int n)
{
    constexpr int HF = 128, WR = 136;     // HF in BYTES (fp8)
    constexpr int CTW = OUTN / 64;        // col-tiles per wave
    constexpr int CPW = OUTN / 4;         // cols per wave
    constexpr int C = 768;                // edge chunk capacity
    __shared__ _Float16 actT[16 * WR];    // act rows; reused for out staging
    __shared__ float red_s[4][16], red_d[4][16];
    __shared__ int soff[17];
    __shared__ unsigned short esrc[C];
    __shared__ float ew[2][C];

    const int t = threadIdx.x;
    const int node0 = blockIdx.x * 16;

    if (t < 17) {
        int nd = node0 + t; nd = nd < n ? nd : n;
        soff[t] = off[nd];
    }
    __syncthreads();
    const int blk0 = soff[0];
    const int blkE = soff[16] - blk0;

    const int l = t & 15;
    const int nl = t >> 4;
    const int c0 = l * 8;                 // byte & col offset (1B/col)
    const int head = l >> 3;
    const int s0 = soff[nl] - blk0;       // block-local edge range
    const int s1 = soff[nl + 1] - blk0;

    float a0 = 0.f, a1 = 0.f, a2 = 0.f, a3 = 0.f;
    float a4 = 0.f, a5 = 0.f, a6 = 0.f, a7 = 0.f, wsum = 0.f;

    for (int cbase = 0; cbase < blkE; cbase += C) {
        const int cend = min(blkE, cbase + C);

        // ---- phase A: per-edge meta, once per edge, coalesced csr ----
        for (int i = cbase + t; i < cend; i += 256) {
            int src = csr[blk0 + i];
            int lo = 0, hi = 16;          // binary search dst node
            while (hi - lo > 1) {
                int mid = (lo + hi) >> 1;
                if (soff[mid] - blk0 <= i) lo = mid; else hi = mid;
            }
            int dst = node0 + lo;
            float2 as2 = *(const float2*)&alS[src * 2];
            float2 ad2 = *(const float2*)&alD[dst * 2];
            float e0 = as2.x + ad2.x; e0 = e0 > 0.f ? e0 : 0.2f * e0;
            float e1 = as2.y + ad2.y; e1 = e1 > 0.f ? e1 : 0.2f * e1;
            esrc[i - cbase] = (unsigned short)src;
            ew[0][i - cbase] = __expf(e0);
            ew[1][i - cbase] = __expf(e1);
        }
        __syncthreads();

        // ---- phase B: pipelined gather over [lo,hi) of this chunk ----
        const int lo = (s0 > cbase ? s0 : cbase) - cbase;
        const int hi = (s1 < cend ? s1 : cend) - cbase;
        if (lo < hi) {
            int sk[4]; float wk[4]; uint2 hv[4];
#pragma unroll
            for (int k = 0; k < 4; k++) {
                int jj = lo + k < hi ? lo + k : hi - 1;
                sk[k] = esrc[jj];
                wk[k] = (lo + k < hi) ? ew[head][jj] : 0.f;
            }
#pragma unroll
            for (int k = 0; k < 4; k++)
                hv[k] = *(const uint2*)&h[(size_t)sk[k] * HF + c0];

            for (int j = lo; j < hi; j += 4) {
                int ns[4]; float nw[4]; uint2 nv[4];
#pragma unroll
                for (int k = 0; k < 4; k++) {
                    int jj = j + 4 + k < hi ? j + 4 + k : hi - 1;
                    ns[k] = esrc[jj];
                    nw[k] = (j + 4 + k < hi) ? ew[head][jj] : 0.f;
                }
#pragma unroll
                for (int k = 0; k < 4; k++)
                    nv[k] = *(const uint2*)&h[(size_t)ns[k] * HF + c0];
#pragma unroll
                for (int k = 0; k < 4; k++) {
                    float w = wk[k];
                    f32x2 f0 = __builtin_amdgcn_cvt_pk_f32_fp8(hv[k].x, false);
                    f32x2 f1 = __builtin_amdgcn_cvt_pk_f32_fp8(hv[k].x, true);
                    f32x2 f2 = __builtin_amdgcn_cvt_pk_f32_fp8(hv[k].y, false);
                    f32x2 f3 = __builtin_amdgcn_cvt_pk_f32_fp8(hv[k].y, true);
                    a0 = fmaf(w, f0.x, a0); a1 = fmaf(w, f0.y, a1);
                    a2 = fmaf(w, f1.x, a2); a3 = fmaf(w, f1.y, a3);
                    a4 = fmaf(w, f2.x, a4); a5 = fmaf(w, f2.y, a5);
                    a6 = fmaf(w, f3.x, a6); a7 = fmaf(w, f3.y, a7);
                    wsum += w;
                }
#pragma unroll
                for (int k = 0; k < 4; k++) { sk[k] = ns[k]; wk[k] = nw[k]; hv[k] = nv[k]; }
            }
        }
        __syncthreads();                  // before next chunk overwrites LDS
    }

    {
        const float inv = 1.f / (wsum + 1e-16f);
        float4 b0 = *(const float4*)&bias[c0];
        float4 b1 = *(const float4*)&bias[c0 + 4];
        float o[8];
        o[0] = ELU(fmaf(a0, inv, b0.x));
        o[1] = ELU(fmaf(a1, inv, b0.y));
        o[2] = ELU(fmaf(a2, inv, b0.z));
        o[3] = ELU(fmaf(a3, inv, b0.w));
        o[4] = ELU(fmaf(a4, inv, b1.x));
        o[5] = ELU(fmaf(a5, inv, b1.y));
        o[6] = ELU(fmaf(a6, inv, b1.z));
        o[7] = ELU(fmaf(a7, inv, b1.w));
        __half2 p[4];
#pragma unroll
        for (int k = 0; k < 4; k++) p[k] = __floats2half2_rn(o[2 * k], o[2 * k + 1]);
        *(float4*)&actT[nl * WR + l * 8] = *(float4*)p;
    }
    __syncthreads();

    // ---- GEMM: D[node][col] = act @ Wt^T, B-fragments from global Wt ----
    const int w = t >> 6, l64 = t & 63, q = l64 >> 4, nn = l64 & 15;
    const __half* Wp = Wt + (size_t)(w * CPW + nn) * 128 + q * 8;
    f32x4 acc[CTW];
#pragma unroll
    for (int ct = 0; ct < CTW; ct++) acc[ct] = (f32x4){0.f, 0.f, 0.f, 0.f};
#pragma unroll
    for (int ks = 0; ks < 4; ks++) {
        f16x8 a = *(const f16x8*)&actT[nn * WR + ks * 32 + q * 8];
#pragma unroll
        for (int ct = 0; ct < CTW; ct++) {
            f16x8 bb = *(const f16x8*)(Wp + ct * 16 * 128 + ks * 32);
            acc[ct] = __builtin_amdgcn_mfma_f32_16x16x32_f16(a, bb, acc[ct], 0, 0, 0);
        }
    }

    // alS/alD partials: reduce over this wave's cols, then across waves (LDS)
    float asv[CTW], adv2[CTW];
#pragma unroll
    for (int ct = 0; ct < CTW; ct++) {
        asv[ct]  = a_s[w * CPW + ct * 16 + nn];
        adv2[ct] = a_d[w * CPW + ct * 16 + nn];
    }
#pragma unroll
    for (int r = 0; r < 4; r++) {
        float s = 0.f, d = 0.f;
#pragma unroll
        for (int ct = 0; ct < CTW; ct++) {
            float vv = acc[ct][r];
            s = fmaf(vv, asv[ct], s);
            d = fmaf(vv, adv2[ct], d);
        }
#pragma unroll
        for (int m = 1; m < 16; m <<= 1) {
            s += __shfl_xor(s, m);
            d += __shfl_xor(d, m);
        }
        if (nn == 0) { red_s[w][q * 4 + r] = s; red_d[w][q * 4 + r] = d; }
    }
    __syncthreads();

    // stage output into actT (reuse) + combine alS across waves
#pragma unroll
    for (int ct = 0; ct < CTW; ct++)
#pragma unroll
        for (int r = 0; r < 4; r++)
            actT[(q * 4 + r) * WR + w * CPW + ct * 16 + nn] = (_Float16)acc[ct][r];
    if (OUTN == 128) {
        if (t < 32) {
            int m = t & 15, hh = t >> 4;
            int grow = node0 + m;
            if (grow < n) {
                alSo[grow * 2 + hh] = red_s[2 * hh][m] + red_s[2 * hh + 1][m];
                alDo[grow * 2 + hh] = red_d[2 * hh][m] + red_d[2 * hh + 1][m];
            }
        }
    } else {
        if (t < 16) {
            int grow = node0 + t;
            if (grow < n) {
                alSo[grow] = red_s[0][t] + red_s[1][t] + red_s[2][t] + red_s[3][t];
                alDo[grow] = red_d[0][t] + red_d[1][t] + red_d[2][t] + red_d[3][t];
            }
        }
    }
    __syncthreads();

    // coalesced Hout store (fp8)
    if (OUTN == 128) {
        int row = t >> 4, c = t & 15;         // 16 lanes x 8 cols
        int grow = node0 + row;
        if (grow < n) {
            float4 v8 = *(float4*)&actT[row * WR + c * 8];
            const __half2* hp = (const __half2*)&v8;
            uint2 o;
            o.x = f16x4_to_fp8(hp[0], hp[1]);
            o.y = f16x4_to_fp8(hp[2], hp[3]);
            *(uint2*)&Hout[(size_t)grow * 128 + c * 8] = o;
        }
    } else {
        if (t < 128) {
            int row = t >> 3, c = t & 7;      // 8 lanes x 8 cols
            int grow = node0 + row;
            if (grow < n) {
                float4 v8 = *(float4*)&actT[row * WR + c * 8];
                const __half2* hp = (const __half2*)&v8;
                uint2 o;
                o.x = f16x4_to_fp8(hp[0], hp[1]);
                o.y = f16x4_to_fp8(hp[2], hp[3]);
                *(uint2*)&Hout[(size_t)grow * 64 + c * 8] = o;
            }
        }
    }
}

// ---------------- final gather (H=1, fp8 h) -> fp32 out --------------------
// R22 phase A/B structure: 32 nodes/block, 8 lanes/node, C=1280.
__global__ __launch_bounds__(256) void gat_gather_out(
    const int* __restrict__ off, const unsigned short* __restrict__ csr,
    const unsigned char* __restrict__ h, const float* __restrict__ alS,
    const float* __restrict__ alD, const float* __restrict__ b,
    float* __restrict__ out, int n)
{
    constexpr int HF = 64;                 // bytes per row (fp8)
    constexpr int C = 1280;
    __shared__ int soff[33];
    __shared__ unsigned short esrc[C];
    __shared__ float ew[C];

    const int t = threadIdx.x;
    const int node0 = blockIdx.x * 32;

    if (t < 33) {
        int nd = node0 + t; nd = nd < n ? nd : n;
        soff[t] = off[nd];
    }
    __syncthreads();
    const int blk0 = soff[0];
    const int blkE = soff[32] - blk0;

    const int l = t & 7;
    const int nl = t >> 3;
    const int node = node0 + nl;
    const int c0 = l * 8;
    const int s0 = soff[nl] - blk0;
    const int s1 = soff[nl + 1] - blk0;

    float a0 = 0.f, a1 = 0.f, a2 = 0.f, a3 = 0.f;
    float a4 = 0.f, a5 = 0.f, a6 = 0.f, a7 = 0.f, wsum = 0.f;

    for (int cbase = 0; cbase < blkE; cbase += C) {
        const int cend = min(blkE, cbase + C);

        for (int i = cbase + t; i < cend; i += 256) {
            int src = csr[blk0 + i];
            int lo = 0, hi = 32;
            while (hi - lo > 1) {
                int mid = (lo + hi) >> 1;
                if (soff[mid] - blk0 <= i) lo = mid; else hi = mid;
            }
            int dst = node0 + lo;
            float e = alS[src] + alD[dst];
            e = e > 0.f ? e : 0.2f * e;
            esrc[i - cbase] = (unsigned short)src;
            ew[i - cbase] = __expf(e);
        }
        __syncthreads();

        const int lo = (s0 > cbase ? s0 : cbase) - cbase;
        const int hi = (s1 < cend ? s1 : cend) - cbase;
        if (lo < hi) {
            int sk[4]; float wk[4]; uint2 hv[4];
#pragma unroll
            for (int k = 0; k < 4; k++) {
                int jj = lo + k < hi ? lo + k : hi - 1;
                sk[k] = esrc[jj];
                wk[k] = (lo + k < hi) ? ew[jj] : 0.f;
            }
#pragma unroll
            for (int k = 0; k < 4; k++)
                hv[k] = *(const uint2*)&h[(size_t)sk[k] * HF + c0];

            for (int j = lo; j < hi; j += 4) {
                int ns[4]; float nw[4]; uint2 nv[4];
#pragma unroll
                for (int k = 0; k < 4; k++) {
                    int jj = j + 4 + k < hi ? j + 4 + k : hi - 1;
                    ns[k] = esrc[jj];
                    nw[k] = (j + 4 + k < hi) ? ew[jj] : 0.f;
                }
#pragma unroll
                for (int k = 0; k < 4; k++)
                    nv[k] = *(const uint2*)&h[(size_t)ns[k] * HF + c0];
#pragma unroll
                for (int k = 0; k < 4; k++) {
                    float w = wk[k];
                    f32x2 f0 = __builtin_amdgcn_cvt_pk_f32_fp8(hv[k].x, false);
                    f32x2 f1 = __builtin_amdgcn_cvt_pk_f32_fp8(hv[k].x, true);
                    f32x2 f2 = __builtin_amdgcn_cvt_pk_f32_fp8(hv[k].y, false);
                    f32x2 f3 = __builtin_amdgcn_cvt_pk_f32_fp8(hv[k].y, true);
                    a0 = fmaf(w, f0.x, a0); a1 = fmaf(w, f0.y, a1);
                    a2 = fmaf(w, f1.x, a2); a3 = fmaf(w, f1.y, a3);
                    a4 = fmaf(w, f2.x, a4); a5 = fmaf(w, f2.y, a5);
                    a6 = fmaf(w, f3.x, a6); a7 = fmaf(w, f3.y, a7);
                    wsum += w;
                }
#pragma unroll
                for (int k = 0; k < 4; k++) { sk[k] = ns[k]; wk[k] = nw[k]; hv[k] = nv[k]; }
            }
        }
        __syncthreads();
    }

    if (node >= n) return;
    const float inv = 1.f / (wsum + 1e-16f);
    float4 b0 = *(const float4*)&b[c0];
    float4 b1 = *(const float4*)&b[c0 + 4];
    float4 o0, o1;
    o0.x = ELU(fmaf(a0, inv, b0.x));
    o0.y = ELU(fmaf(a1, inv, b0.y));
    o0.z = ELU(fmaf(a2, inv, b0.z));
    o0.w = ELU(fmaf(a3, inv, b0.w));
    o1.x = ELU(fmaf(a4, inv, b1.x));
    o1.y = ELU(fmaf(a5, inv, b1.y));
    o1.z = ELU(fmaf(a6, inv, b1.z));
    o1.w = ELU(fmaf(a7, inv, b1.w));
    *(float4*)&out[(size_t)node * HF + c0]     = o0;
    *(float4*)&out[(size_t)node * HF + c0 + 4] = o1;
}

extern "C" void kernel_launch(void* const* d_in, const int* in_sizes, int n_in,
                              void* d_out, int out_size, void* d_ws, size_t ws_size,
                              hipStream_t stream)
{
    const float* x   = (const float*)d_in[0];
    const float* W1  = (const float*)d_in[1];
    const float* as1 = (const float*)d_in[2];
    const float* ad1 = (const float*)d_in[3];
    const float* b1  = (const float*)d_in[4];
    const float* W2  = (const float*)d_in[5];
    const float* as2 = (const float*)d_in[6];
    const float* ad2 = (const float*)d_in[7];
    const float* b2  = (const float*)d_in[8];
    const float* W3  = (const float*)d_in[9];
    const float* as3 = (const float*)d_in[10];
    const float* ad3 = (const float*)d_in[11];
    const float* b3  = (const float*)d_in[12];
    const int*   ei  = (const int*)d_in[13];
    float* out = (float*)d_out;

    const int N_   = in_sizes[0] / 128;     // 50000
    const int E_   = in_sizes[13] / 2;      // 1600000
    const int Etot = E_ + N_;
    const int NB   = (N_ + 255) >> BSH;     // 196 buckets
    const int HB   = (E_ + CHK - 1) / CHK;  // 196 hist/partition blocks

    char* ws = (char*)d_ws;
    size_t o = 0;
    auto alloc = [&](size_t bytes) { void* p = ws + o; o += (bytes + 255) & ~255ull; return p; };
    unsigned char* h1 = (unsigned char*)alloc((size_t)N_ * 128);
    unsigned char* h2 = (unsigned char*)alloc((size_t)N_ * 128);
    unsigned char* h3 = (unsigned char*)alloc((size_t)N_ * 64);
    __half* Wt1   = (__half*)alloc((size_t)128 * 128 * 2);
    __half* Wt2   = (__half*)alloc((size_t)128 * 128 * 2);
    __half* Wt3   = (__half*)alloc((size_t)64 * 128 * 2);
    float* alSa   = (float*)alloc((size_t)N_ * 2 * 4);
    float* alDa   = (float*)alloc((size_t)N_ * 2 * 4);
    float* alSb   = (float*)alloc((size_t)N_ * 2 * 4);
    float* alDb   = (float*)alloc((size_t)N_ * 2 * 4);
    int*   offb   = (int*)alloc((size_t)(N_ + 1) * 4);
    int*   bhrows = (int*)alloc((size_t)HB * 256 * 4);
    int*   boff   = (int*)alloc((size_t)257 * 4);
    int*   bases  = (int*)alloc((size_t)256 * HB * 4);
    int*   part   = (int*)alloc((size_t)Etot * 4);
    unsigned short* csr = (unsigned short*)alloc((size_t)Etot * 2);

    const dim3 blk(256);

    // ---- CSR build (deterministic counting sort, no global atomics) ----
    phase0<<<160 + HB, blk, 0, stream>>>(W1, Wt1, W2, Wt2, W3, Wt3, ei, bhrows, E_);
    scan_bases<<<NB, blk, 0, stream>>>(bhrows, boff, bases, part, HB, N_, NB);
    edge_partition<<<HB, blk, 0, stream>>>(ei, bases, part, E_, HB, NB);
    bucket_fill<<<NB, blk, 0, stream>>>(boff, part, csr, offb, N_);

    // ---- layer pipeline ----
    gemm1_mfma<<<(N_ + 63) / 64, blk, 0, stream>>>(x, Wt1, h1, as1, ad1, alSa, alDa, N_);
    gat_gather_gemm<128><<<(N_ + 15) / 16, blk, 0, stream>>>(
        offb, csr, h1, alSa, alDa, b1, Wt2, as2, ad2, h2, alSb, alDb, N_);
    gat_gather_gemm<64><<<(N_ + 15) / 16, blk, 0, stream>>>(
        offb, csr, h2, alSb, alDb, b2, Wt3, as3, ad3, h3, alSa, alDa, N_);
    gat_gather_out<<<(N_ + 31) / 32, blk, 0, stream>>>(
        offb, csr, h3, alSa, alDa, b3, out, N_);
}

// Round 10
// 251.196 us; speedup vs baseline: 2.1459x; 1.1483x over previous
//
#include <hip/hip_runtime.h>
#include <hip/hip_bf16.h>
#include <hip/hip_fp16.h>

// ---------------------------------------------------------------------------
// 3-layer GAT encoder. N=50000, E=1600000 (+N self loops), H=2 (layers 1-2),
// F=64 per head, F_IN=128.
// R13: deterministic counting-sort CSR + fused gather/GEMM: 337us.
// R16: h fp8 e4m3, fused gather+GEMM: gg 52.5us/61.5MB FETCH, 294us.
// R17/R18 NEG, R19 FAILED (write-allocate), R20/R21 (L2 pinning works but
//      un-fusing costs more).
// R22: LDS per-edge meta (phase A once-per-edge w=exp(leaky), phase B
//      R16-pipelined gather with LDS broadcast): gg 50.3us, 288us. BEST.
//      gg is AT its latency floor: 211MB/50us = 4.2TB/s line-fill ~= the
//      64-slot x ~170ns ceiling. Stop touching gg.
// R23: the rest pool (~188us). CSR chain ran 196 blocks x 256 thr =
//      4 waves/CU on 77% of CUs -> duration = single-block latency.
//      Widen all 4 chain kernels to 1024 thr/block (4x waves, 8 edges/thr);
//      scans stay 256-wide (guarded), scan_bases row-sum split 4-way.
//      Algorithm unchanged (R19 lesson: never scattered global writes).
//      gg/gout/gemm1 untouched.
// ---------------------------------------------------------------------------

#define ELU(x) ((x) > 0.f ? (x) : (__expf(x) - 1.f))
#define BSH 8                       // 256 nodes per bucket
#define CHK 8192                    // edges per histogram/partition block

typedef _Float16 f16x8 __attribute__((ext_vector_type(8)));
typedef float    f32x4 __attribute__((ext_vector_type(4)));
typedef float    f32x2 __attribute__((ext_vector_type(2)));

// pack 4 f16 (as 2 half2) -> 4 fp8 e4m3 in one dword (RNE in HW)
__device__ inline unsigned int f16x4_to_fp8(__half2 h0, __half2 h1) {
    float2 a = __half22float2(h0), b = __half22float2(h1);
    unsigned int r = __builtin_amdgcn_cvt_pk_fp8_f32(a.x, a.y, 0, false);
    r = __builtin_amdgcn_cvt_pk_fp8_f32(b.x, b.y, r, true);
    return r;
}

// ---------------- phase0 (1024 thr): Wt builds + dst histogram rows --------
// blocks 0..39: Wt transposes (40*1024 = 40960 = total Wt elements).
// blocks 40..: histogram row per CHK edges.
__global__ __launch_bounds__(1024) void phase0(
    const float* __restrict__ W1, __half* __restrict__ Wt1,
    const float* __restrict__ W2, __half* __restrict__ Wt2,
    const float* __restrict__ W3, __half* __restrict__ Wt3,
    const int* __restrict__ ei, int* __restrict__ bhist_rows, int E_)
{
    const int t = threadIdx.x;
    const int b = blockIdx.x;
    if (b < 40) {
        int idx = b * 1024 + t;                      // 0..40959
        const float* W; __half* Wt; int N;
        if (idx < 16384)      { W = W1; Wt = Wt1; N = 128; }
        else if (idx < 32768) { W = W2; Wt = Wt2; N = 128; idx -= 16384; }
        else                  { W = W3; Wt = Wt3; N = 64;  idx -= 32768; }
        int nn = idx >> 7, k = idx & 127;
        Wt[idx] = __float2half(W[k * N + nn]);
    } else {                                         // dst histogram row
        __shared__ int cnt[256];
        int hb = b - 40;
        if (t < 256) cnt[t] = 0;
        __syncthreads();
        const int e0 = hb * CHK;
        for (int i = t; i < CHK; i += 1024) {
            int e = e0 + i;
            if (e >= E_) break;
            atomicAdd(&cnt[ei[E_ + e] >> BSH], 1);
        }
        __syncthreads();
        if (t < 256) bhist_rows[hb * 256 + t] = cnt[t];
    }
}

// one block per bucket (1024 thr): (a) bucket totals + scan (block 0 writes
// boff), (b) column scan -> per-partition-block bases, (c) self-loop tail.
__global__ __launch_bounds__(1024) void scan_bases(
    const int* __restrict__ bhist_rows, int* __restrict__ boff,
    int* __restrict__ bases, int* __restrict__ part, int HB, int n, int NB)
{
    __shared__ int part4[4][256];
    __shared__ int tot[256];
    __shared__ int col[256];
    const int t = threadIdx.x;
    const int b = blockIdx.x;                        // bucket

    // bucket totals: 4-way split row-sum over HB rows
    {
        const int tcol = t & 255, grp = t >> 8;
        int v = 0;
        for (int r = grp; r < HB; r += 4) v += bhist_rows[r * 256 + tcol];
        part4[grp][tcol] = v;
    }
    __syncthreads();
    if (t < 256) {
        int v = part4[0][t] + part4[1][t] + part4[2][t] + part4[3][t];
        int nodes_t = n - (t << BSH);
        nodes_t = nodes_t < 0 ? 0 : (nodes_t > 256 ? 256 : nodes_t);
        tot[t] = (t < NB) ? (v + nodes_t) : 0;
    }
    __syncthreads();
    for (int d = 1; d < 256; d <<= 1) {
        int x = 0;
        if (t < 256 && t >= d) x = tot[t - d];
        __syncthreads();
        if (t < 256 && t >= d) tot[t] += x;
        __syncthreads();
    }
    if (b == 0) {
        if (t < NB) boff[t + 1] = tot[t];
        if (t == 0) boff[0] = 0;
    }
    const int base0 = (b > 0) ? tot[b - 1] : 0;      // boff[b]
    const int bend  = tot[b];                        // boff[b+1]

    // column scan for this bucket -> bases
    if (t < 256) col[t] = (t < HB) ? bhist_rows[t * 256 + b] : 0;
    __syncthreads();
    for (int d = 1; d < 256; d <<= 1) {
        int x = 0;
        if (t < 256 && t >= d) x = col[t - d];
        __syncthreads();
        if (t < 256 && t >= d) col[t] += x;
        __syncthreads();
    }
    if (t < HB) {
        int c = bhist_rows[t * 256 + b];
        bases[b * HB + t] = base0 + col[t] - c;      // exclusive
    }

    // self loops at bucket tail (coalesced); src < 65536 fits low 16 bits
    const int n0 = b << BSH;
    const int nodes = min(256, n - n0);
    const int sl0 = bend - nodes;
    if (t < nodes) part[sl0 + t] = (n0 + t) | (t << 16);
}

// single-pass partition (1024 thr): deterministic bases, LDS cursors.
// packed entry: src (bits 0..15) | dst_local (bits 16..23)
__global__ __launch_bounds__(1024) void edge_partition(
    const int* __restrict__ ei, const int* __restrict__ bases,
    int* __restrict__ part, int E_, int HB, int NB)
{
    __shared__ int cnt[256];
    __shared__ int sbase[256];
    const int t = threadIdx.x;
    const int hb = blockIdx.x;
    if (t < 256) {
        cnt[t] = 0;
        sbase[t] = (t < NB) ? bases[t * HB + hb] : 0;
    }
    __syncthreads();
    const int e0 = hb * CHK;
    for (int i = t; i < CHK; i += 1024) {
        int e = e0 + i;
        if (e >= E_) break;
        int src = ei[e], dst = ei[E_ + e];
        int b = dst >> BSH;
        int pos = sbase[b] + atomicAdd(&cnt[b], 1);
        part[pos] = src | ((dst & 255) << 16);
    }
}

// one block per bucket (1024 thr): degree count, scan -> off[], place, flush
// csr output is ushort (src < 65536).
__global__ __launch_bounds__(1024) void bucket_fill(
    const int* __restrict__ boff, const int* __restrict__ part,
    unsigned short* __restrict__ csr, int* __restrict__ off, int n)
{
    __shared__ int sm[256];
    __shared__ int cur[256];
    __shared__ int slice[12544];
    const int t = threadIdx.x;
    const int b = blockIdx.x;
    const int n0 = b << BSH;
    const int nodes = min(256, n - n0);
    const int off0 = boff[b];
    const int sz = boff[b + 1] - off0;

    if (t < 256) cur[t] = 0;
    __syncthreads();
    for (int i = t; i < sz; i += 1024)
        atomicAdd(&cur[(part[off0 + i] >> 16) & 255], 1);
    __syncthreads();
    int v = 0;
    if (t < 256) { v = cur[t]; sm[t] = v; }
    __syncthreads();
    for (int d = 1; d < 256; d <<= 1) {
        int x = 0;
        if (t < 256 && t >= d) x = sm[t - d];
        __syncthreads();
        if (t < 256 && t >= d) sm[t] += x;
        __syncthreads();
    }
    if (t < 256) {
        const int excl = sm[t] - v;
        if (t < nodes) off[n0 + t] = off0 + excl;
        if (t == nodes - 1) off[n0 + nodes] = off0 + sz;
        cur[t] = excl;
    }
    __syncthreads();

    if (sz <= 12544) {
        for (int i = t; i < sz; i += 1024) {
            int p  = part[off0 + i];
            int dl = (p >> 16) & 255;
            int pos = atomicAdd(&cur[dl], 1);
            slice[pos] = p & 0xFFFF;
        }
        __syncthreads();
        for (int i = t; i < sz; i += 1024)
            csr[off0 + i] = (unsigned short)slice[i];
    } else {                                     // fallback (shouldn't trigger)
        for (int i = t; i < sz; i += 1024) {
            int p  = part[off0 + i];
            int dl = (p >> 16) & 255;
            int pos = atomicAdd(&cur[dl], 1);
            csr[off0 + pos] = (unsigned short)(p & 0xFFFF);
        }
    }
}

// ---------------- layer-1 MFMA GEMM (fp32 A, LDS W) -> fp8 h1 (128B rows) --
__global__ __launch_bounds__(256) void gemm1_mfma(
    const float* __restrict__ A, const __half* __restrict__ Wt, // [128][128]
    unsigned char* __restrict__ Hout, const float* __restrict__ a_s,
    const float* __restrict__ a_d, float* __restrict__ alS,
    float* __restrict__ alD, int nrows)
{
    constexpr int N = 128, NT = 8, WR = 136;
    __shared__ _Float16 wt[N * WR];
    __shared__ _Float16 hst[4][16 * WR];

    const int t = threadIdx.x, w = t >> 6, l = t & 63;
    const int q = l >> 4, n = l & 15;
    const int node0 = blockIdx.x * 64;
    const int row_base = node0 + w * 16;

    for (int i = t; i < N * 16; i += 256) {
        int r = i >> 4, c = i & 15;
        float4 v = *(const float4*)&Wt[r * 128 + c * 8];
        *(float4*)&wt[r * WR + c * 8] = v;
    }
    __syncthreads();

    f32x4 acc[NT];
#pragma unroll
    for (int ct = 0; ct < NT; ct++) acc[ct] = (f32x4){0.f, 0.f, 0.f, 0.f};

    int arow = row_base + n; if (arow >= nrows) arow = nrows - 1;
    const float* Ap = A + (size_t)arow * 128 + q * 8;
#pragma unroll
    for (int ks = 0; ks < 4; ks++) {
        float4 va = *(const float4*)(Ap + ks * 32);
        float4 vb = *(const float4*)(Ap + ks * 32 + 4);
        f16x8 a = { (_Float16)va.x, (_Float16)va.y, (_Float16)va.z, (_Float16)va.w,
                    (_Float16)vb.x, (_Float16)vb.y, (_Float16)vb.z, (_Float16)vb.w };
#pragma unroll
        for (int ct = 0; ct < NT; ct++) {
            f16x8 bb = *(const f16x8*)&wt[(ct * 16 + n) * WR + ks * 32 + q * 8];
            acc[ct] = __builtin_amdgcn_mfma_f32_16x16x32_f16(a, bb, acc[ct], 0, 0, 0);
        }
    }

    float asv[NT], adv[NT];
#pragma unroll
    for (int ct = 0; ct < NT; ct++) {
        asv[ct] = a_s[ct * 16 + n];
        adv[ct] = a_d[ct * 16 + n];
    }
#pragma unroll
    for (int r = 0; r < 4; r++) {
        int grow = row_base + q * 4 + r;
        float s0 = 0.f, d0 = 0.f, s1 = 0.f, d1 = 0.f;
#pragma unroll
        for (int ct = 0; ct < NT; ct++) {
            float v = acc[ct][r];
            float ps = v * asv[ct], pd = v * adv[ct];
            if (ct >= 4) { s1 += ps; d1 += pd; }
            else         { s0 += ps; d0 += pd; }
        }
#pragma unroll
        for (int m = 1; m < 16; m <<= 1) {
            s0 += __shfl_xor(s0, m); d0 += __shfl_xor(d0, m);
            s1 += __shfl_xor(s1, m); d1 += __shfl_xor(d1, m);
        }
        if (n == 0 && grow < nrows) {
            alS[grow * 2] = s0;     alD[grow * 2] = d0;
            alS[grow * 2 + 1] = s1; alD[grow * 2 + 1] = d1;
        }
    }

#pragma unroll
    for (int ct = 0; ct < NT; ct++)
#pragma unroll
        for (int r = 0; r < 4; r++)
            hst[w][(q * 4 + r) * WR + ct * 16 + n] = (_Float16)acc[ct][r];
    __syncthreads();
    {
        int row = l >> 2, c = l & 3;            // 4 lanes x 32 cols
        int grow = row_base + row;
        if (grow < nrows) {
#pragma unroll
            for (int i = 0; i < 4; i++) {
                float4 v = *(float4*)&hst[w][row * WR + c * 32 + i * 8];
                const __half2* hp = (const __half2*)&v;
                uint2 o;
                o.x = f16x4_to_fp8(hp[0], hp[1]);
                o.y = f16x4_to_fp8(hp[2], hp[3]);
                *(uint2*)&Hout[(size_t)grow * 128 + c * 32 + i * 8] = o;
            }
        }
    }
}

// ---------------- fused gather (H=2) + next-layer GEMM ---------------------
// R22: phase A computes per-edge meta once into LDS; phase B = R16 depth-4+4
// pipelined gather with LDS-broadcast meta. Fused GEMM epilogue unchanged.
template<int OUTN>
__global__ __launch_bounds__(256) void gat_gather_gemm(
    const int* __restrict__ off, const unsigned short* __restrict__ csr,
    const unsigned char* __restrict__ h, const float* __restrict__ alS,
    const float* __restrict__ alD, const float* __restrict__ bias,
    const __half* __restrict__ Wt, const float* __restrict__ a_s,
    const float* __restrict__ a_d, unsigned char* __restrict__ Hout,
    float* __restrict__ alSo, float* __restrict__ alDo, int n)
{
    constexpr int HF = 128, WR = 136;     // HF in BYTES (fp8)
    constexpr int CTW = OUTN / 64;        // col-tiles per wave
    constexpr int CPW = OUTN / 4;         // cols per wave
    constexpr int C = 768;                // edge chunk capacity
    __shared__ _Float16 actT[16 * WR];    // act rows; reused for out staging
    __shared__ float red_s[4][16], red_d[4][16];
    __shared__ int soff[17];
    __shared__ unsigned short esrc[C];
    __shared__ float ew[2][C];

    const int t = threadIdx.x;
    const int node0 = blockIdx.x * 16;

    if (t < 17) {
        int nd = node0 + t; nd = nd < n ? nd : n;
        soff[t] = off[nd];
    }
    __syncthreads();
    const int blk0 = soff[0];
    const int blkE = soff[16] - blk0;

    const int l = t & 15;
    const int nl = t >> 4;
    const int c0 = l * 8;                 // byte & col offset (1B/col)
    const int head = l >> 3;
    const int s0 = soff[nl] - blk0;       // block-local edge range
    const int s1 = soff[nl + 1] - blk0;

    float a0 = 0.f, a1 = 0.f, a2 = 0.f, a3 = 0.f;
    float a4 = 0.f, a5 = 0.f, a6 = 0.f, a7 = 0.f, wsum = 0.f;

    for (int cbase = 0; cbase < blkE; cbase += C) {
        const int cend = min(blkE, cbase + C);

        // ---- phase A: per-edge meta, once per edge, coalesced csr ----
        for (int i = cbase + t; i < cend; i += 256) {
            int src = csr[blk0 + i];
            int lo = 0, hi = 16;          // binary search dst node
            while (hi - lo > 1) {
                int mid = (lo + hi) >> 1;
                if (soff[mid] - blk0 <= i) lo = mid; else hi = mid;
            }
            int dst = node0 + lo;
            float2 as2 = *(const float2*)&alS[src * 2];
            float2 ad2 = *(const float2*)&alD[dst * 2];
            float e0 = as2.x + ad2.x; e0 = e0 > 0.f ? e0 : 0.2f * e0;
            float e1 = as2.y + ad2.y; e1 = e1 > 0.f ? e1 : 0.2f * e1;
            esrc[i - cbase] = (unsigned short)src;
            ew[0][i - cbase] = __expf(e0);
            ew[1][i - cbase] = __expf(e1);
        }
        __syncthreads();

        // ---- phase B: pipelined gather over [lo,hi) of this chunk ----
        const int lo = (s0 > cbase ? s0 : cbase) - cbase;
        const int hi = (s1 < cend ? s1 : cend) - cbase;
        if (lo < hi) {
            int sk[4]; float wk[4]; uint2 hv[4];
#pragma unroll
            for (int k = 0; k < 4; k++) {
                int jj = lo + k < hi ? lo + k : hi - 1;
                sk[k] = esrc[jj];
                wk[k] = (lo + k < hi) ? ew[head][jj] : 0.f;
            }
#pragma unroll
            for (int k = 0; k < 4; k++)
                hv[k] = *(const uint2*)&h[(size_t)sk[k] * HF + c0];

            for (int j = lo; j < hi; j += 4) {
                int ns[4]; float nw[4]; uint2 nv[4];
#pragma unroll
                for (int k = 0; k < 4; k++) {
                    int jj = j + 4 + k < hi ? j + 4 + k : hi - 1;
                    ns[k] = esrc[jj];
                    nw[k] = (j + 4 + k < hi) ? ew[head][jj] : 0.f;
                }
#pragma unroll
                for (int k = 0; k < 4; k++)
                    nv[k] = *(const uint2*)&h[(size_t)ns[k] * HF + c0];
#pragma unroll
                for (int k = 0; k < 4; k++) {
                    float w = wk[k];
                    f32x2 f0 = __builtin_amdgcn_cvt_pk_f32_fp8(hv[k].x, false);
                    f32x2 f1 = __builtin_amdgcn_cvt_pk_f32_fp8(hv[k].x, true);
                    f32x2 f2 = __builtin_amdgcn_cvt_pk_f32_fp8(hv[k].y, false);
                    f32x2 f3 = __builtin_amdgcn_cvt_pk_f32_fp8(hv[k].y, true);
                    a0 = fmaf(w, f0.x, a0); a1 = fmaf(w, f0.y, a1);
                    a2 = fmaf(w, f1.x, a2); a3 = fmaf(w, f1.y, a3);
                    a4 = fmaf(w, f2.x, a4); a5 = fmaf(w, f2.y, a5);
                    a6 = fmaf(w, f3.x, a6); a7 = fmaf(w, f3.y, a7);
                    wsum += w;
                }
#pragma unroll
                for (int k = 0; k < 4; k++) { sk[k] = ns[k]; wk[k] = nw[k]; hv[k] = nv[k]; }
            }
        }
        __syncthreads();                  // before next chunk overwrites LDS
    }

    {
        const float inv = 1.f / (wsum + 1e-16f);
        float4 b0 = *(const float4*)&bias[c0];
        float4 b1 = *(const float4*)&bias[c0 + 4];
        float o[8];
        o[0] = ELU(fmaf(a0, inv, b0.x));
        o[1] = ELU(fmaf(a1, inv, b0.y));
        o[2] = ELU(fmaf(a2, inv, b0.z));
        o[3] = ELU(fmaf(a3, inv, b0.w));
        o[4] = ELU(fmaf(a4, inv, b1.x));
        o[5] = ELU(fmaf(a5, inv, b1.y));
        o[6] = ELU(fmaf(a6, inv, b1.z));
        o[7] = ELU(fmaf(a7, inv, b1.w));
        __half2 p[4];
#pragma unroll
        for (int k = 0; k < 4; k++) p[k] = __floats2half2_rn(o[2 * k], o[2 * k + 1]);
        *(float4*)&actT[nl * WR + l * 8] = *(float4*)p;
    }
    __syncthreads();

    // ---- GEMM: D[node][col] = act @ Wt^T, B-fragments from global Wt ----
    const int w = t >> 6, l64 = t & 63, q = l64 >> 4, nn = l64 & 15;
    const __half* Wp = Wt + (size_t)(w * CPW + nn) * 128 + q * 8;
    f32x4 acc[CTW];
#pragma unroll
    for (int ct = 0; ct < CTW; ct++) acc[ct] = (f32x4){0.f, 0.f, 0.f, 0.f};
#pragma unroll
    for (int ks = 0; ks < 4; ks++) {
        f16x8 a = *(const f16x8*)&actT[nn * WR + ks * 32 + q * 8];
#pragma unroll
        for (int ct = 0; ct < CTW; ct++) {
            f16x8 bb = *(const f16x8*)(Wp + ct * 16 * 128 + ks * 32);
            acc[ct] = __builtin_amdgcn_mfma_f32_16x16x32_f16(a, bb, acc[ct], 0, 0, 0);
        }
    }

    // alS/alD partials: reduce over this wave's cols, then across waves (LDS)
    float asv[CTW], adv2[CTW];
#pragma unroll
    for (int ct = 0; ct < CTW; ct++) {
        asv[ct]  = a_s[w * CPW + ct * 16 + nn];
        adv2[ct] = a_d[w * CPW + ct * 16 + nn];
    }
#pragma unroll
    for (int r = 0; r < 4; r++) {
        float s = 0.f, d = 0.f;
#pragma unroll
        for (int ct = 0; ct < CTW; ct++) {
            float vv = acc[ct][r];
            s = fmaf(vv, asv[ct], s);
            d = fmaf(vv, adv2[ct], d);
        }
#pragma unroll
        for (int m = 1; m < 16; m <<= 1) {
            s += __shfl_xor(s, m);
            d += __shfl_xor(d, m);
        }
        if (nn == 0) { red_s[w][q * 4 + r] = s; red_d[w][q * 4 + r] = d; }
    }
    __syncthreads();

    // stage output into actT (reuse) + combine alS across waves
#pragma unroll
    for (int ct = 0; ct < CTW; ct++)
#pragma unroll
        for (int r = 0; r < 4; r++)
            actT[(q * 4 + r) * WR + w * CPW + ct * 16 + nn] = (_Float16)acc[ct][r];
    if (OUTN == 128) {
        if (t < 32) {
            int m = t & 15, hh = t >> 4;
            int grow = node0 + m;
            if (grow < n) {
                alSo[grow * 2 + hh] = red_s[2 * hh][m] + red_s[2 * hh + 1][m];
                alDo[grow * 2 + hh] = red_d[2 * hh][m] + red_d[2 * hh + 1][m];
            }
        }
    } else {
        if (t < 16) {
            int grow = node0 + t;
            if (grow < n) {
                alSo[grow] = red_s[0][t] + red_s[1][t] + red_s[2][t] + red_s[3][t];
                alDo[grow] = red_d[0][t] + red_d[1][t] + red_d[2][t] + red_d[3][t];
            }
        }
    }
    __syncthreads();

    // coalesced Hout store (fp8)
    if (OUTN == 128) {
        int row = t >> 4, c = t & 15;         // 16 lanes x 8 cols
        int grow = node0 + row;
        if (grow < n) {
            float4 v8 = *(float4*)&actT[row * WR + c * 8];
            const __half2* hp = (const __half2*)&v8;
            uint2 o;
            o.x = f16x4_to_fp8(hp[0], hp[1]);
            o.y = f16x4_to_fp8(hp[2], hp[3]);
            *(uint2*)&Hout[(size_t)grow * 128 + c * 8] = o;
        }
    } else {
        if (t < 128) {
            int row = t >> 3, c = t & 7;      // 8 lanes x 8 cols
            int grow = node0 + row;
            if (grow < n) {
                float4 v8 = *(float4*)&actT[row * WR + c * 8];
                const __half2* hp = (const __half2*)&v8;
                uint2 o;
                o.x = f16x4_to_fp8(hp[0], hp[1]);
                o.y = f16x4_to_fp8(hp[2], hp[3]);
                *(uint2*)&Hout[(size_t)grow * 64 + c * 8] = o;
            }
        }
    }
}

// ---------------- final gather (H=1, fp8 h) -> fp32 out --------------------
// R22 phase A/B structure: 32 nodes/block, 8 lanes/node, C=1280.
__global__ __launch_bounds__(256) void gat_gather_out(
    const int* __restrict__ off, const unsigned short* __restrict__ csr,
    const unsigned char* __restrict__ h, const float* __restrict__ alS,
    const float* __restrict__ alD, const float* __restrict__ b,
    float* __restrict__ out, int n)
{
    constexpr int HF = 64;                 // bytes per row (fp8)
    constexpr int C = 1280;
    __shared__ int soff[33];
    __shared__ unsigned short esrc[C];
    __shared__ float ew[C];

    const int t = threadIdx.x;
    const int node0 = blockIdx.x * 32;

    if (t < 33) {
        int nd = node0 + t; nd = nd < n ? nd : n;
        soff[t] = off[nd];
    }
    __syncthreads();
    const int blk0 = soff[0];
    const int blkE = soff[32] - blk0;

    const int l = t & 7;
    const int nl = t >> 3;
    const int node = node0 + nl;
    const int c0 = l * 8;
    const int s0 = soff[nl] - blk0;
    const int s1 = soff[nl + 1] - blk0;

    float a0 = 0.f, a1 = 0.f, a2 = 0.f, a3 = 0.f;
    float a4 = 0.f, a5 = 0.f, a6 = 0.f, a7 = 0.f, wsum = 0.f;

    for (int cbase = 0; cbase < blkE; cbase += C) {
        const int cend = min(blkE, cbase + C);

        for (int i = cbase + t; i < cend; i += 256) {
            int src = csr[blk0 + i];
            int lo = 0, hi = 32;
            while (hi - lo > 1) {
                int mid = (lo + hi) >> 1;
                if (soff[mid] - blk0 <= i) lo = mid; else hi = mid;
            }
            int dst = node0 + lo;
            float e = alS[src] + alD[dst];
            e = e > 0.f ? e : 0.2f * e;
            esrc[i - cbase] = (unsigned short)src;
            ew[i - cbase] = __expf(e);
        }
        __syncthreads();

        const int lo = (s0 > cbase ? s0 : cbase) - cbase;
        const int hi = (s1 < cend ? s1 : cend) - cbase;
        if (lo < hi) {
            int sk[4]; float wk[4]; uint2 hv[4];
#pragma unroll
            for (int k = 0; k < 4; k++) {
                int jj = lo + k < hi ? lo + k : hi - 1;
                sk[k] = esrc[jj];
                wk[k] = (lo + k < hi) ? ew[jj] : 0.f;
            }
#pragma unroll
            for (int k = 0; k < 4; k++)
                hv[k] = *(const uint2*)&h[(size_t)sk[k] * HF + c0];

            for (int j = lo; j < hi; j += 4) {
                int ns[4]; float nw[4]; uint2 nv[4];
#pragma unroll
                for (int k = 0; k < 4; k++) {
                    int jj = j + 4 + k < hi ? j + 4 + k : hi - 1;
                    ns[k] = esrc[jj];
                    nw[k] = (j + 4 + k < hi) ? ew[jj] : 0.f;
                }
#pragma unroll
                for (int k = 0; k < 4; k++)
                    nv[k] = *(const uint2*)&h[(size_t)ns[k] * HF + c0];
#pragma unroll
                for (int k = 0; k < 4; k++) {
                    float w = wk[k];
                    f32x2 f0 = __builtin_amdgcn_cvt_pk_f32_fp8(hv[k].x, false);
                    f32x2 f1 = __builtin_amdgcn_cvt_pk_f32_fp8(hv[k].x, true);
                    f32x2 f2 = __builtin_amdgcn_cvt_pk_f32_fp8(hv[k].y, false);
                    f32x2 f3 = __builtin_amdgcn_cvt_pk_f32_fp8(hv[k].y, true);
                    a0 = fmaf(w, f0.x, a0); a1 = fmaf(w, f0.y, a1);
                    a2 = fmaf(w, f1.x, a2); a3 = fmaf(w, f1.y, a3);
                    a4 = fmaf(w, f2.x, a4); a5 = fmaf(w, f2.y, a5);
                    a6 = fmaf(w, f3.x, a6); a7 = fmaf(w, f3.y, a7);
                    wsum += w;
                }
#pragma unroll
                for (int k = 0; k < 4; k++) { sk[k] = ns[k]; wk[k] = nw[k]; hv[k] = nv[k]; }
            }
        }
        __syncthreads();
    }

    if (node >= n) return;
    const float inv = 1.f / (wsum + 1e-16f);
    float4 b0 = *(const float4*)&b[c0];
    float4 b1 = *(const float4*)&b[c0 + 4];
    float4 o0, o1;
    o0.x = ELU(fmaf(a0, inv, b0.x));
    o0.y = ELU(fmaf(a1, inv, b0.y));
    o0.z = ELU(fmaf(a2, inv, b0.z));
    o0.w = ELU(fmaf(a3, inv, b0.w));
    o1.x = ELU(fmaf(a4, inv, b1.x));
    o1.y = ELU(fmaf(a5, inv, b1.y));
    o1.z = ELU(fmaf(a6, inv, b1.z));
    o1.w = ELU(fmaf(a7, inv, b1.w));
    *(float4*)&out[(size_t)node * HF + c0]     = o0;
    *(float4*)&out[(size_t)node * HF + c0 + 4] = o1;
}

extern "C" void kernel_launch(void* const* d_in, const int* in_sizes, int n_in,
                              void* d_out, int out_size, void* d_ws, size_t ws_size,
                              hipStream_t stream)
{
    const float* x   = (const float*)d_in[0];
    const float* W1  = (const float*)d_in[1];
    const float* as1 = (const float*)d_in[2];
    const float* ad1 = (const float*)d_in[3];
    const float* b1  = (const float*)d_in[4];
    const float* W2  = (const float*)d_in[5];
    const float* as2 = (const float*)d_in[6];
    const float* ad2 = (const float*)d_in[7];
    const float* b2  = (const float*)d_in[8];
    const float* W3  = (const float*)d_in[9];
    const float* as3 = (const float*)d_in[10];
    const float* ad3 = (const float*)d_in[11];
    const float* b3  = (const float*)d_in[12];
    const int*   ei  = (const int*)d_in[13];
    float* out = (float*)d_out;

    const int N_   = in_sizes[0] / 128;     // 50000
    const int E_   = in_sizes[13] / 2;      // 1600000
    const int Etot = E_ + N_;
    const int NB   = (N_ + 255) >> BSH;     // 196 buckets
    const int HB   = (E_ + CHK - 1) / CHK;  // 196 hist/partition blocks

    char* ws = (char*)d_ws;
    size_t o = 0;
    auto alloc = [&](size_t bytes) { void* p = ws + o; o += (bytes + 255) & ~255ull; return p; };
    unsigned char* h1 = (unsigned char*)alloc((size_t)N_ * 128);
    unsigned char* h2 = (unsigned char*)alloc((size_t)N_ * 128);
    unsigned char* h3 = (unsigned char*)alloc((size_t)N_ * 64);
    __half* Wt1   = (__half*)alloc((size_t)128 * 128 * 2);
    __half* Wt2   = (__half*)alloc((size_t)128 * 128 * 2);
    __half* Wt3   = (__half*)alloc((size_t)64 * 128 * 2);
    float* alSa   = (float*)alloc((size_t)N_ * 2 * 4);
    float* alDa   = (float*)alloc((size_t)N_ * 2 * 4);
    float* alSb   = (float*)alloc((size_t)N_ * 2 * 4);
    float* alDb   = (float*)alloc((size_t)N_ * 2 * 4);
    int*   offb   = (int*)alloc((size_t)(N_ + 1) * 4);
    int*   bhrows = (int*)alloc((size_t)HB * 256 * 4);
    int*   boff   = (int*)alloc((size_t)257 * 4);
    int*   bases  = (int*)alloc((size_t)256 * HB * 4);
    int*   part   = (int*)alloc((size_t)Etot * 4);
    unsigned short* csr = (unsigned short*)alloc((size_t)Etot * 2);

    const dim3 blk(256);
    const dim3 blk1k(1024);

    // ---- CSR build (deterministic counting sort, 1024-thread blocks) ----
    phase0<<<40 + HB, blk1k, 0, stream>>>(W1, Wt1, W2, Wt2, W3, Wt3, ei, bhrows, E_);
    scan_bases<<<NB, blk1k, 0, stream>>>(bhrows, boff, bases, part, HB, N_, NB);
    edge_partition<<<HB, blk1k, 0, stream>>>(ei, bases, part, E_, HB, NB);
    bucket_fill<<<NB, blk1k, 0, stream>>>(boff, part, csr, offb, N_);

    // ---- layer pipeline ----
    gemm1_mfma<<<(N_ + 63) / 64, blk, 0, stream>>>(x, Wt1, h1, as1, ad1, alSa, alDa, N_);
    gat_gather_gemm<128><<<(N_ + 15) / 16, blk, 0, stream>>>(
        offb, csr, h1, alSa, alDa, b1, Wt2, as2, ad2, h2, alSb, alDb, N_);
    gat_gather_gemm<64><<<(N_ + 15) / 16, blk, 0, stream>>>(
        offb, csr, h2, alSb, alDb, b2, Wt3, as3, ad3, h3, alSa, alDa, N_);
    gat_gather_out<<<(N_ + 31) / 32, blk, 0, stream>>>(
        offb, csr, h3, alSa, alDa, b3, out, N_);
}